// Round 20
// baseline (457.515 us; speedup 1.0000x reference)
//
#include <hip/hip_runtime.h>
#include <hip/hip_fp16.h>

#define EPS_BN 1e-5f

typedef __attribute__((ext_vector_type(8))) short bf16x8;
typedef __attribute__((ext_vector_type(4))) float f32x4;
typedef _Float16 h2 __attribute__((ext_vector_type(2)));

#if defined(__has_builtin)
#if __has_builtin(__builtin_amdgcn_fdot2)
#define HAVE_FDOT2 1
#endif
#endif

// ---------------- workspace layout (float-unit offsets) ----------------
#define O_SRCD   0u
#define O_DSTD   17024u
#define O_COUNTS 34048u
#define O_OFFS   35072u
#define O_CURS   36096u
#define O_PW1    54144u                    // [32][640]  (Wl1T|Wr1T|WpT)
#define O_PW2    74624u                    // PW2B: 131072 bf16 B-frags (Wl2|Wr2)
#define O_LW     140160u                   // PHHB (262144 bf16) + PWB (262144 bf16)
#define O_BCOMB  402304u                   // [2][128j][4]  (gp order)
#define O_ABF    403328u                   // A1(256)|B1(256)|A2(128)|B2(128)
#define O_HWT    404352u                   // Ws1T(832)|Ws2T(2048)|Wh1T(10240)
#define O_BIG0   417536u                   // XL1(fp16) | XL2(fp16) | PRE(fp16)
#define O_BIG1   (O_BIG0 + 16384000u)      // XR1(bf16) | XR2(bf16 at +8192000)
#define O_BIG2   (O_BIG1 + 16384000u)      // H1(bf16)  | h1seq(bf16)
#define O_BIG3   (O_BIG2 + 16384000u)      // XP(bf16)  | LO(bf16)
#define O_BIG4   (O_BIG3 + 8192000u)       // Hres(bf16)
#define O_SXL    (O_BIG4 + 8192000u)       // SXL1 [64][1001][2] | SXL2 [64][1001] | C1F | C2F | EPAD
#define O_SXL2   (O_SXL + 128128u)
#define O_C1F    (O_SXL + 192192u)
#define O_C2F    (O_SXL + 192256u)
#define O_EPAD   (O_SXL + 192512u)         // esrc padded (24064 ints, sentinel=1000)

#define LOG2E 1.4426950408889634f

__device__ __forceinline__ float rsum32(float p) {
  p += __shfl_xor(p, 1);  p += __shfl_xor(p, 2);  p += __shfl_xor(p, 4);
  p += __shfl_xor(p, 8);  p += __shfl_xor(p, 16); return p;
}
__device__ __forceinline__ float rsum64(float p) {
  p = rsum32(p); p += __shfl_xor(p, 32); return p;
}
__device__ __forceinline__ float eluf(float x)  { return x > 0.f ? x : expm1f(x); }
__device__ __forceinline__ float geluf(float x) { return 0.5f * x * (1.f + erff(x * 0.70710678118654752f)); }
__device__ __forceinline__ unsigned short f2bf(float f) {
  unsigned int u = __float_as_uint(f);
  u += 0x7FFFu + ((u >> 16) & 1u);
  return (unsigned short)(u >> 16);
}
__device__ __forceinline__ float bf2f(unsigned short h) {
  return __uint_as_float(((unsigned int)h) << 16);
}
__device__ __forceinline__ unsigned short f2h(float x) {
  __half h = __float2half(x);
  return *reinterpret_cast<unsigned short*>(&h);
}
__device__ __forceinline__ float h2f(unsigned short u) {
  __half h = *reinterpret_cast<__half*>(&u);
  return __half2float(h);
}
__device__ __forceinline__ void unpk(unsigned int w, float& lo, float& hi) {
  lo = __uint_as_float(w << 16);
  hi = __uint_as_float(w & 0xFFFF0000u);
}
__device__ __forceinline__ void unpk8(uint4 u, float (&x)[8]) {
  unpk(u.x, x[0], x[1]); unpk(u.y, x[2], x[3]);
  unpk(u.z, x[4], x[5]); unpk(u.w, x[6], x[7]);
}
__device__ __forceinline__ h2 h2bits(unsigned int w) {
  return *reinterpret_cast<h2*>(&w);
}
__device__ __forceinline__ unsigned int bitsh2(h2 v) {
  return *reinterpret_cast<unsigned int*>(&v);
}
__device__ __forceinline__ h2 habs2v(h2 v) {
  unsigned int u = bitsh2(v) & 0x7FFF7FFFu;
  return h2bits(u);
}
__device__ __forceinline__ float dot2f(h2 a, h2 b, float c) {
#ifdef HAVE_FDOT2
  return __builtin_amdgcn_fdot2(a, b, c, false);
#else
  return fmaf((float)a[1], (float)b[1], fmaf((float)a[0], (float)b[0], c));
#endif
}
// packed logit: sum_k a_k * |x_k + xr_k| over 8 features (a pre-scaled by 0.4*log2e)
__device__ __forceinline__ float gat_logit(uint4 u, const h2* xrh, const h2* avh) {
  float p = 0.f;
  p = dot2f(habs2v(h2bits(u.x) + xrh[0]), avh[0], p);
  p = dot2f(habs2v(h2bits(u.y) + xrh[1]), avh[1], p);
  p = dot2f(habs2v(h2bits(u.z) + xrh[2]), avh[2], p);
  p = dot2f(habs2v(h2bits(u.w) + xrh[3]), avh[3], p);
  return p;
}

// ---------------- prep kernels (parallel, 4 small) ----------------
__global__ void prep_edges(const int* __restrict__ ei, int* __restrict__ srcD,
                           int* __restrict__ dstD, int* __restrict__ counts,
                           int* __restrict__ esrcp) {
  int i = blockIdx.x * 256 + threadIdx.x;
  if (i < 1024) counts[i] = 0;
  if (i < 24064) esrcp[i] = 1000;          // sentinel row
  if (i < 17000) {
    int s = (i < 16000) ? ei[i] : (i - 16000);
    int d = (i < 16000) ? ei[16000 + i] : (i - 16000);
    srcD[i] = s; dstD[i] = d;
  }
}
__global__ void hist_kernel(const int* __restrict__ dstD, int* __restrict__ counts) {
  int i = blockIdx.x * 256 + threadIdx.x;
  if (i < 17000) atomicAdd(&counts[dstD[i]], 1);
}
__global__ void scan_kernel(const int* __restrict__ counts, int* __restrict__ offs,
                            int* __restrict__ curs) {
  __shared__ int sh[1024];
  int i = threadIdx.x;
  int v = (i < 1000) ? counts[i] : 0;
  int vp = (v + 7) & ~7;                   // pad each node's edges to multiple of 8
  sh[i] = vp;
  __syncthreads();
  for (int d = 1; d < 1024; d <<= 1) {
    int t = (i >= d) ? sh[i - d] : 0;
    __syncthreads();
    sh[i] += t;
    __syncthreads();
  }
  if (i < 1000) { offs[i + 1] = sh[i]; curs[i] = sh[i] - vp; }
  if (i == 0) offs[0] = 0;
}
__global__ void fill_kernel(const int* __restrict__ srcD, const int* __restrict__ dstD,
                            int* __restrict__ curs, int* __restrict__ esrc) {
  int i = blockIdx.x * 256 + threadIdx.x;
  if (i < 17000) { int p = atomicAdd(&curs[dstD[i]], 1); esrc[p] = srcD[i]; }
}

// PHHB/PWB: hh/ih weights split-bf16 MFMA B-frags [L][split][kc4][gt32][lane64][e8]
// PW2B: GAT2 proj weights split-bf16 B-frags [sp][kc8][ct16][lane64][e8]
// C1F/C2F pre-scaled by 0.6*log2e
__global__ void pack_kernel(
    const float* __restrict__ Wl1, const float* __restrict__ Wr1, const float* __restrict__ Wp,
    const float* __restrict__ Wl2, const float* __restrict__ Wr2,
    const float* __restrict__ Wih0, const float* __restrict__ Whh0,
    const float* __restrict__ bih0, const float* __restrict__ bhh0,
    const float* __restrict__ Wih1, const float* __restrict__ Whh1,
    const float* __restrict__ bih1, const float* __restrict__ bhh1,
    const float* __restrict__ g1, const float* __restrict__ be1, const float* __restrict__ m1,
    const float* __restrict__ v1, const float* __restrict__ bg1,
    const float* __restrict__ g2, const float* __restrict__ be2, const float* __restrict__ m2,
    const float* __restrict__ v2, const float* __restrict__ bg2,
    const float* __restrict__ Ws1, const float* __restrict__ Ws2, const float* __restrict__ Wh1,
    const float* __restrict__ a1, const float* __restrict__ a2,
    float* __restrict__ PW1, unsigned short* __restrict__ PW2Bu,
    unsigned short* __restrict__ PHHBu, unsigned short* __restrict__ PWBu,
    float* __restrict__ BC, float* __restrict__ ABF, float* __restrict__ HWT,
    float* __restrict__ C1F, float* __restrict__ C2F,
    float* __restrict__ SXL1, float* __restrict__ SXL2)
{
  int i = blockIdx.x * 256 + threadIdx.x;
  if (i < 262144) {  // PHHB + PWB split-bf16
    int e = i & 7, lane = (i >> 3) & 63, gt = (i >> 9) & 31,
        kc = (i >> 14) & 3, sp = (i >> 16) & 1, L = (i >> 17) & 1;
    int gp = (gt << 4) + (lane & 15);
    int jj = gp >> 2, gate = gp & 3;
    int kk = (kc << 5) + ((lane >> 4) << 3) + e;
    const float* Wih = L ? Wih1 : Wih0;
    const float* Whh = L ? Whh1 : Whh0;
    float wv = Wih[(gate * 128 + jj) * 128 + kk];
    unsigned short hi = f2bf(wv);
    PWBu[i] = (sp == 0) ? hi : f2bf(wv - bf2f(hi));
    float hv = Whh[(gate * 128 + jj) * 128 + kk];
    unsigned short hhi = f2bf(hv);
    PHHBu[i] = (sp == 0) ? hhi : f2bf(hv - bf2f(hhi));
  }
  if (i < 131072) {  // PW2B split-bf16 B-frags
    int e = i & 7, lane = (i >> 3) & 63, ct = (i >> 9) & 15,
        kc = (i >> 13) & 7, sp = (i >> 16) & 1;
    int c = (ct << 4) + (lane & 15);
    int k = (kc << 5) + ((lane >> 4) << 3) + e;
    float wv2 = (c < 128) ? Wl2[c * 256 + k] : Wr2[(c - 128) * 256 + k];
    unsigned short hi = f2bf(wv2);
    PW2Bu[i] = (sp == 0) ? hi : f2bf(wv2 - bf2f(hi));
  }
  if (i < 20480) { int g = i % 640, k = i / 640;
    PW1[i] = (g < 256) ? Wl1[g * 32 + k] : (g < 512) ? Wr1[(g - 256) * 32 + k]
                                                     : Wp[(g - 512) * 32 + k]; }
  if (i < 1024) { int u = i & 3, jj = (i >> 2) & 127, L = i >> 9;
    BC[i] = (L ? bih1 : bih0)[u * 128 + jj] + (L ? bhh1 : bhh0)[u * 128 + jj]; }
  if (i < 768) {
    if (i < 256) ABF[i] = g1[i] * rsqrtf(v1[i] + EPS_BN);
    else if (i < 512) { int c = i - 256; float a = g1[c] * rsqrtf(v1[c] + EPS_BN);
      ABF[i] = (bg1[c] - m1[c]) * a + be1[c]; }
    else if (i < 640) { int c = i - 512; ABF[i] = g2[c] * rsqrtf(v2[c] + EPS_BN); }
    else { int c = i - 640; float a = g2[c] * rsqrtf(v2[c] + EPS_BN);
      ABF[i] = (bg2[c] - m2[c]) * a + be2[c]; }
  }
  if (i < 13120) {
    if (i < 832) { int l = i & 63, c = i >> 6; HWT[i] = Ws1[l * 13 + c]; }
    else if (i < 2880) { int k = i - 832; int l = k & 31, jj = k >> 5; HWT[i] = Ws2[l * 64 + jj]; }
    else { int k = i - 2880; int l = k & 63, r = k >> 6; HWT[i] = Wh1[l * 160 + r]; }
  }
  if (i < 64) {   // C1F (pre-scaled 0.6*log2e)
    int k = i & 31, h = i >> 5;
    float s = 0.f;
    for (int j = 0; j < 128; ++j)
      s = fmaf(a1[h * 128 + j], Wl1[(h * 128 + j) * 32 + k], s);
    C1F[i] = 0.6f * LOG2E * s;
  }
  if (i < 256) {  // C2F (pre-scaled 0.6*log2e)
    float s = 0.f;
    for (int c = 0; c < 128; ++c)
      s = fmaf(a2[c], Wl2[c * 256 + i], s);
    C2F[i] = 0.6f * LOG2E * s;
  }
  if (i < 128) {  // SXL1 sentinels: row 1000 of each graph
    int bb = i >> 1;
    SXL1[(size_t)bb * 2002 + 2000 + (i & 1)] = -1e30f;
  }
  if (i < 64) {   // SXL2 sentinels
    SXL2[(size_t)i * 1001 + 1000] = -1e30f;
  }
}

// ---------------- projection 1 (+fused slx1): x -> xl1(fp16)|xr1(bf16)|xp(bf16) + SXL1 --
__global__ __launch_bounds__(320)
void proj1_kernel(const float* __restrict__ X, const float* __restrict__ PW1,
                  const float* __restrict__ bp, const float* __restrict__ C1F,
                  unsigned short* __restrict__ XL1u,
                  unsigned short* __restrict__ XR1u, unsigned short* __restrict__ XPu,
                  float* __restrict__ SXL1)
{
  __shared__ __align__(16) float xs[32][16];
  const int tid = threadIdx.x;
  const int r0 = blockIdx.x * 16;
  for (int el = tid; el < 512; el += 320) {
    int r = el >> 5, k = el & 31;
    xs[k][r] = X[(size_t)(r0 + r) * 32 + k];
  }
  __syncthreads();
  if (tid < 32) {                       // slx1 = dot(C1F[h], x_row), pre-scaled 0.6*log2e
    int r = tid & 15, h = tid >> 4;
    const float* c1 = C1F + h * 32;
    float s = 0.f;
    for (int k = 0; k < 32; ++k) s = fmaf(c1[k], xs[k][r], s);
    int row = r0 + r;
    int bb = row / 1000;
    int nn = row - bb * 1000;
    SXL1[(size_t)bb * 2002 + nn * 2 + h] = s;
  }
  const int gA = tid, gB = tid + 320;
  float accA[16], accB[16];
  const float iB = (gB >= 512) ? bp[gB - 512] : 0.f;
  #pragma unroll
  for (int r = 0; r < 16; ++r) { accA[r] = 0.f; accB[r] = iB; }
  for (int k = 0; k < 32; ++k) {
    float wA = PW1[k * 640 + gA], wB = PW1[k * 640 + gB];
    float xv[16];
    #pragma unroll
    for (int q = 0; q < 4; ++q)
      *reinterpret_cast<float4*>(&xv[q * 4]) = *reinterpret_cast<const float4*>(&xs[k][q * 4]);
    #pragma unroll
    for (int r = 0; r < 16; ++r) {
      accA[r] = fmaf(wA, xv[r], accA[r]);
      accB[r] = fmaf(wB, xv[r], accB[r]);
    }
  }
  for (int r = 0; r < 16; ++r) {
    size_t row = r0 + r;
    if (gA < 256) XL1u[row * 256 + gA] = f2h(accA[r]);        // fp16
    else          XR1u[row * 256 + (gA - 256)] = f2bf(accA[r]);
    if (gB < 512) XR1u[row * 256 + (gB - 256)] = f2bf(accB[r]);
    else          XPu[row * 128 + (gB - 512)] = f2bf(accB[r]);
  }
}

// ---------------- GAT layer 1: padded CSR, exp2, packed fp16; 4 edges/wave-iter -------
__global__ __launch_bounds__(256)
__attribute__((amdgpu_waves_per_eu(4)))
void gat1_kernel(const unsigned short* __restrict__ XLu, const unsigned short* __restrict__ XRu,
                 const float* __restrict__ SXL,
                 const int* __restrict__ esrc, const int* __restrict__ offs,
                 const float* __restrict__ a1, const float* __restrict__ ABF,
                 const float* __restrict__ C2F,
                 unsigned short* __restrict__ H1u, float* __restrict__ SXL2)
{
  const int lane = threadIdx.x & 63;
  const int wv = threadIdx.x >> 6;
  const int n = blockIdx.x * 4 + wv;
  const int b = blockIdx.y;
  const int epar = lane >> 5;              // edge parity
  const int head = (lane >> 4) & 1;
  const int li = lane & 15;
  const int f0 = head * 128 + li * 8;
  const int beg = offs[n];
  const int degp = offs[n + 1] - beg;      // multiple of 8, >= 8
  const char* XLbase = (const char*)XLu + (size_t)b * 512000u;   // 1000 rows * 512 B
  const float* SXLb = SXL + (size_t)b * 2002;
  const unsigned fb = (unsigned)(f0 * 2);
  h2 xrh[4], avh[4];
  {
    const uint4* xrp = reinterpret_cast<const uint4*>(XRu + (size_t)(b * 1000 + n) * 256 + f0);
    float xr[8]; unpk8(xrp[0], xr);
    const float* ap = a1 + f0;
    float4 a0 = *reinterpret_cast<const float4*>(ap);
    float4 a1v = *reinterpret_cast<const float4*>(ap + 4);
    float av[8] = {a0.x, a0.y, a0.z, a0.w, a1v.x, a1v.y, a1v.z, a1v.w};
    const float asc = 0.4f * LOG2E;
    #pragma unroll
    for (int k = 0; k < 4; ++k) {
      h2 t; t[0] = (_Float16)xr[2 * k]; t[1] = (_Float16)xr[2 * k + 1]; xrh[k] = t;
      h2 s; s[0] = (_Float16)(av[2 * k] * asc); s[1] = (_Float16)(av[2 * k + 1] * asc); avh[k] = s;
    }
  }
  float ssum = 0.f;
  h2 acch[4];
  #pragma unroll
  for (int k = 0; k < 4; ++k) { h2 z; z[0] = (_Float16)0.f; z[1] = (_Float16)0.f; acch[k] = z; }
  // slots A (edge i0+epar) and B (edge i0+2+epar), step 4; pads have slx=-1e30 -> we=0
  unsigned sA = (unsigned)esrc[beg + epar];
  unsigned sB = (unsigned)esrc[beg + 2 + epar];
  uint4 uA = *reinterpret_cast<const uint4*>(XLbase + (size_t)((sA << 9) + fb));
  uint4 uB = *reinterpret_cast<const uint4*>(XLbase + (size_t)((sB << 9) + fb));
  float slA = SXLb[sA * 2 + head];
  float slB = SXLb[sB * 2 + head];
  for (int i0 = 0; i0 < degp; i0 += 4) {
    unsigned tA = (unsigned)esrc[beg + i0 + 4 + epar];
    unsigned tB = (unsigned)esrc[beg + i0 + 6 + epar];
    uint4 puA = *reinterpret_cast<const uint4*>(XLbase + (size_t)((tA << 9) + fb));
    uint4 puB = *reinterpret_cast<const uint4*>(XLbase + (size_t)((tB << 9) + fb));
    float pslA = SXLb[tA * 2 + head];
    float pslB = SXLb[tB * 2 + head];
    float pA = gat_logit(uA, xrh, avh);
    float pB = gat_logit(uB, xrh, avh);
    pA += __shfl_xor(pA, 1); pB += __shfl_xor(pB, 1);
    pA += __shfl_xor(pA, 2); pB += __shfl_xor(pB, 2);
    pA += __shfl_xor(pA, 4); pB += __shfl_xor(pB, 4);
    pA += __shfl_xor(pA, 8); pB += __shfl_xor(pB, 8);
    float weA = exp2f(pA + slA);           // slA=-1e30 on pad -> 0
    float weB = exp2f(pB + slB);
    ssum += weA + weB;
    h2 wA2; wA2[0] = (_Float16)weA; wA2[1] = wA2[0];
    h2 wB2; wB2[0] = (_Float16)weB; wB2[1] = wB2[0];
    acch[0] = wA2 * h2bits(uA.x) + acch[0];
    acch[1] = wA2 * h2bits(uA.y) + acch[1];
    acch[2] = wA2 * h2bits(uA.z) + acch[2];
    acch[3] = wA2 * h2bits(uA.w) + acch[3];
    acch[0] = wB2 * h2bits(uB.x) + acch[0];
    acch[1] = wB2 * h2bits(uB.y) + acch[1];
    acch[2] = wB2 * h2bits(uB.z) + acch[2];
    acch[3] = wB2 * h2bits(uB.w) + acch[3];
    uA = puA; uB = puB; slA = pslA; slB = pslB;
  }
  // merge edge-parity halves (same head): lane ^ 32
  ssum += __shfl_xor(ssum, 32);
  float inv = 1.f / ssum;
  float acc[8];
  #pragma unroll
  for (int k = 0; k < 4; ++k) {
    unsigned ob = (unsigned)__shfl_xor((int)bitsh2(acch[k]), 32);
    h2 m = acch[k] + h2bits(ob);
    acc[2 * k] = (float)m[0];
    acc[2 * k + 1] = (float)m[1];
  }
  float A4[8], B4[8];
  {
    const float* aap = ABF + f0;
    float4 t0 = *reinterpret_cast<const float4*>(aap);
    float4 t1 = *reinterpret_cast<const float4*>(aap + 4);
    A4[0]=t0.x; A4[1]=t0.y; A4[2]=t0.z; A4[3]=t0.w;
    A4[4]=t1.x; A4[5]=t1.y; A4[6]=t1.z; A4[7]=t1.w;
    const float* bbp = ABF + 256 + f0;
    float4 s0v = *reinterpret_cast<const float4*>(bbp);
    float4 s1v = *reinterpret_cast<const float4*>(bbp + 4);
    B4[0]=s0v.x; B4[1]=s0v.y; B4[2]=s0v.z; B4[3]=s0v.w;
    B4[4]=s1v.x; B4[5]=s1v.y; B4[6]=s1v.z; B4[7]=s1v.w;
  }
  float o[8];
  #pragma unroll
  for (int k = 0; k < 8; ++k)
    o[k] = eluf(fmaf(acc[k] * inv, A4[k], B4[k]));
  // fused slx2 = dot(C2F, H1row) (pre-scaled 0.6*log2e)
  {
    const float* cp = C2F + f0;
    float4 c0 = *reinterpret_cast<const float4*>(cp);
    float4 c1 = *reinterpret_cast<const float4*>(cp + 4);
    float cc[8] = {c0.x, c0.y, c0.z, c0.w, c1.x, c1.y, c1.z, c1.w};
    float s2 = 0.f;
    #pragma unroll
    for (int k = 0; k < 8; ++k) s2 = fmaf(cc[k], o[k], s2);
    s2 += __shfl_xor(s2, 1); s2 += __shfl_xor(s2, 2);
    s2 += __shfl_xor(s2, 4); s2 += __shfl_xor(s2, 8);
    s2 += __shfl_xor(s2, 16);
    if (lane == 0) SXL2[(size_t)b * 1001 + n] = s2;
  }
  if (lane < 32) {
    unsigned short* hp = H1u + (size_t)(b * 1000 + n) * 256 + f0;
    ushort4 w0 = make_ushort4(f2bf(o[0]), f2bf(o[1]), f2bf(o[2]), f2bf(o[3]));
    ushort4 w1 = make_ushort4(f2bf(o[4]), f2bf(o[5]), f2bf(o[6]), f2bf(o[7]));
    *reinterpret_cast<ushort4*>(hp) = w0;
    *reinterpret_cast<ushort4*>(hp + 4) = w1;
  }
}

// ---------------- projection 2 (MFMA, bf16 A direct): h1 -> xl2(fp16)|xr2(bf16) --------
__global__ __launch_bounds__(512)
void proj2_kernel(const unsigned short* __restrict__ H1u, const unsigned short* __restrict__ PW2B,
                  unsigned short* __restrict__ XL2u, unsigned short* __restrict__ XR2u)
{
  const int tid = threadIdx.x;
  const int lane = tid & 63;
  const int wv = tid >> 6;
  const int l15 = lane & 15;
  const int kg = lane >> 4;
  const int r0 = blockIdx.x * 32;
  f32x4 acc[2][2];
  #pragma unroll
  for (int rt = 0; rt < 2; ++rt)
    #pragma unroll
    for (int ct = 0; ct < 2; ++ct)
      #pragma unroll
      for (int e = 0; e < 4; ++e) acc[rt][ct][e] = 0.f;
  for (int kc = 0; kc < 8; ++kc) {
    bf16x8 xa[2];
    #pragma unroll
    for (int rt = 0; rt < 2; ++rt)
      xa[rt] = *reinterpret_cast<const bf16x8*>(
          H1u + (size_t)(r0 + rt * 16 + l15) * 256 + (kc << 5) + (kg << 3));
    #pragma unroll
    for (int ct = 0; ct < 2; ++ct) {
      const int ctg = (wv << 1) + ct;
      const unsigned short* wp = PW2B + ((size_t)(kc * 16 + ctg)) * 512 + lane * 8;
      bf16x8 whi = *reinterpret_cast<const bf16x8*>(wp);
      bf16x8 wlo = *reinterpret_cast<const bf16x8*>(wp + 65536);
      #pragma unroll
      for (int rt = 0; rt < 2; ++rt) {
        acc[rt][ct] = __builtin_amdgcn_mfma_f32_16x16x32_bf16(xa[rt], whi, acc[rt][ct], 0, 0, 0);
        acc[rt][ct] = __builtin_amdgcn_mfma_f32_16x16x32_bf16(xa[rt], wlo, acc[rt][ct], 0, 0, 0);
      }
    }
  }
  #pragma unroll
  for (int ct = 0; ct < 2; ++ct) {
    const int col = (wv << 5) + (ct << 4) + l15;
    #pragma unroll
    for (int rt = 0; rt < 2; ++rt) {
      #pragma unroll
      for (int reg = 0; reg < 4; ++reg) {
        const int row = r0 + rt * 16 + (kg << 2) + reg;
        float val = acc[rt][ct][reg];
        if (col < 128) XL2u[(size_t)row * 128 + col] = f2h(val);   // fp16
        else           XR2u[(size_t)row * 128 + (col - 128)] = f2bf(val);
      }
    }
  }
}

// ---------------- GAT layer 2: padded CSR, exp2, packed fp16; 8 edges/wave-iter -------
__global__ __launch_bounds__(256)
__attribute__((amdgpu_waves_per_eu(4)))
void gat2_kernel(const unsigned short* __restrict__ XLu, const unsigned short* __restrict__ XRu,
                 const float* __restrict__ SXL,
                 const int* __restrict__ esrc, const int* __restrict__ offs,
                 const float* __restrict__ a2, const float* __restrict__ ABF,
                 const unsigned short* __restrict__ XPu, unsigned short* __restrict__ Hresu)
{
  const int lane = threadIdx.x & 63;
  const int wv = threadIdx.x >> 6;
  const int n = blockIdx.x * 4 + wv;
  const int b = blockIdx.y;
  const int grp = lane >> 4;               // edge slot 0..3
  const int li = lane & 15;
  const int f0 = li * 8;
  const int beg = offs[n];
  const int degp = offs[n + 1] - beg;      // multiple of 8
  const char* XLbase = (const char*)XLu + (size_t)b * 256000u;   // 1000 rows * 256 B
  const float* SXLb = SXL + (size_t)b * 1001;
  const unsigned fb = (unsigned)(f0 * 2);
  h2 xrh[4], avh[4];
  {
    const uint4* xrp = reinterpret_cast<const uint4*>(XRu + (size_t)(b * 1000 + n) * 128 + f0);
    float xr[8]; unpk8(xrp[0], xr);
    const float* ap = a2 + f0;
    float4 a0 = *reinterpret_cast<const float4*>(ap);
    float4 a1v = *reinterpret_cast<const float4*>(ap + 4);
    float av[8] = {a0.x, a0.y, a0.z, a0.w, a1v.x, a1v.y, a1v.z, a1v.w};
    const float asc = 0.4f * LOG2E;
    #pragma unroll
    for (int k = 0; k < 4; ++k) {
      h2 t; t[0] = (_Float16)xr[2 * k]; t[1] = (_Float16)xr[2 * k + 1]; xrh[k] = t;
      h2 s; s[0] = (_Float16)(av[2 * k] * asc); s[1] = (_Float16)(av[2 * k + 1] * asc); avh[k] = s;
    }
  }
  float ssum = 0.f;
  h2 acch[4];
  #pragma unroll
  for (int k = 0; k < 4; ++k) { h2 z; z[0] = (_Float16)0.f; z[1] = (_Float16)0.f; acch[k] = z; }
  // slots A (edge i0+grp) and B (edge i0+4+grp), step 8; pads -> we=0
  unsigned sA = (unsigned)esrc[beg + grp];
  unsigned sB = (unsigned)esrc[beg + 4 + grp];
  uint4 uA = *reinterpret_cast<const uint4*>(XLbase + (size_t)((sA << 8) + fb));
  uint4 uB = *reinterpret_cast<const uint4*>(XLbase + (size_t)((sB << 8) + fb));
  float slA = SXLb[sA];
  float slB = SXLb[sB];
  for (int i0 = 0; i0 < degp; i0 += 8) {
    unsigned tA = (unsigned)esrc[beg + i0 + 8 + grp];
    unsigned tB = (unsigned)esrc[beg + i0 + 12 + grp];
    uint4 puA = *reinterpret_cast<const uint4*>(XLbase + (size_t)((tA << 8) + fb));
    uint4 puB = *reinterpret_cast<const uint4*>(XLbase + (size_t)((tB << 8) + fb));
    float pslA = SXLb[tA];
    float pslB = SXLb[tB];
    float pA = gat_logit(uA, xrh, avh);
    float pB = gat_logit(uB, xrh, avh);
    pA += __shfl_xor(pA, 1); pB += __shfl_xor(pB, 1);
    pA += __shfl_xor(pA, 2); pB += __shfl_xor(pB, 2);
    pA += __shfl_xor(pA, 4); pB += __shfl_xor(pB, 4);
    pA += __shfl_xor(pA, 8); pB += __shfl_xor(pB, 8);
    float weA = exp2f(pA + slA);
    float weB = exp2f(pB + slB);
    ssum += weA + weB;
    h2 wA2; wA2[0] = (_Float16)weA; wA2[1] = wA2[0];
    h2 wB2; wB2[0] = (_Float16)weB; wB2[1] = wB2[0];
    acch[0] = wA2 * h2bits(uA.x) + acch[0];
    acch[1] = wA2 * h2bits(uA.y) + acch[1];
    acch[2] = wA2 * h2bits(uA.z) + acch[2];
    acch[3] = wA2 * h2bits(uA.w) + acch[3];
    acch[0] = wB2 * h2bits(uB.x) + acch[0];
    acch[1] = wB2 * h2bits(uB.y) + acch[1];
    acch[2] = wB2 * h2bits(uB.z) + acch[2];
    acch[3] = wB2 * h2bits(uB.w) + acch[3];
    uA = puA; uB = puB; slA = pslA; slB = pslB;
  }
  // merge 4 edge groups: xor16 then xor32 (plain adds, softmax shift cancels)
  ssum += __shfl_xor(ssum, 16);
  ssum += __shfl_xor(ssum, 32);
  float acc[8];
  #pragma unroll
  for (int k = 0; k < 4; ++k) {
    unsigned o16 = (unsigned)__shfl_xor((int)bitsh2(acch[k]), 16);
    h2 m = acch[k] + h2bits(o16);
    unsigned o32 = (unsigned)__shfl_xor((int)bitsh2(m), 32);
    m = m + h2bits(o32);
    acc[2 * k] = (float)m[0];
    acc[2 * k + 1] = (float)m[1];
  }
  float inv = 1.f / ssum;
  if (lane < 16) {
    const float* aap = ABF + 512 + f0;
    float4 t0 = *reinterpret_cast<const float4*>(aap);
    float4 t1 = *reinterpret_cast<const float4*>(aap + 4);
    const float* bbp = ABF + 640 + f0;
    float4 s0v = *reinterpret_cast<const float4*>(bbp);
    float4 s1v = *reinterpret_cast<const float4*>(bbp + 4);
    float xp8[8];
    unpk8(*reinterpret_cast<const uint4*>(XPu + (size_t)(b * 1000 + n) * 128 + f0), xp8);
    float A4[8] = {t0.x, t0.y, t0.z, t0.w, t1.x, t1.y, t1.z, t1.w};
    float B4[8] = {s0v.x, s0v.y, s0v.z, s0v.w, s1v.x, s1v.y, s1v.z, s1v.w};
    unsigned short* hp = Hresu + (size_t)(b * 1000 + n) * 128 + f0;
    ushort4 w0, w1;
    w0.x = f2bf(eluf(fmaf(acc[0] * inv, A4[0], B4[0])) + xp8[0]);
    w0.y = f2bf(eluf(fmaf(acc[1] * inv, A4[1], B4[1])) + xp8[1]);
    w0.z = f2bf(eluf(fmaf(acc[2] * inv, A4[2], B4[2])) + xp8[2]);
    w0.w = f2bf(eluf(fmaf(acc[3] * inv, A4[3], B4[3])) + xp8[3]);
    w1.x = f2bf(eluf(fmaf(acc[4] * inv, A4[4], B4[4])) + xp8[4]);
    w1.y = f2bf(eluf(fmaf(acc[5] * inv, A4[5], B4[5])) + xp8[5]);
    w1.z = f2bf(eluf(fmaf(acc[6] * inv, A4[6], B4[6])) + xp8[6]);
    w1.w = f2bf(eluf(fmaf(acc[7] * inv, A4[7], B4[7])) + xp8[7]);
    *reinterpret_cast<ushort4*>(hp) = w0;
    *reinterpret_cast<ushort4*>(hp + 4) = w1;
  }
}

// ---------------- MFMA pre-GEMM (bf16 A direct): PRE = fp16( X @ WihT + BC ) ----------
__global__ __launch_bounds__(512)
void gemm_pre_kernel(const unsigned short* __restrict__ Xu, const unsigned short* __restrict__ PWB,
                     const float* __restrict__ BCL, unsigned short* __restrict__ PREh)
{
  const int tid = threadIdx.x;
  const int lane = tid & 63;
  const int wv = tid >> 6;
  const int l15 = lane & 15;
  const int kg = lane >> 4;
  const int r0 = blockIdx.x * 32;
  f32x4 acc[2][4];
  #pragma unroll
  for (int rt = 0; rt < 2; ++rt)
    #pragma unroll
    for (int gt = 0; gt < 4; ++gt)
      #pragma unroll
      for (int e = 0; e < 4; ++e) acc[rt][gt][e] = 0.f;
  for (int kc = 0; kc < 4; ++kc) {
    bf16x8 xa[2];
    #pragma unroll
    for (int rt = 0; rt < 2; ++rt)
      xa[rt] = *reinterpret_cast<const bf16x8*>(
          Xu + (size_t)(r0 + rt * 16 + l15) * 128 + (kc << 5) + (kg << 3));
    #pragma unroll
    for (int gt = 0; gt < 4; ++gt) {
      const int gtg = (wv << 2) + gt;
      const unsigned short* wp = PWB + ((size_t)(kc * 32 + gtg)) * 512 + lane * 8;
      bf16x8 whi = *reinterpret_cast<const bf16x8*>(wp);
      bf16x8 wlo = *reinterpret_cast<const bf16x8*>(wp + 65536);
      #pragma unroll
      for (int rt = 0; rt < 2; ++rt) {
        acc[rt][gt] = __builtin_amdgcn_mfma_f32_16x16x32_bf16(xa[rt], whi, acc[rt][gt], 0, 0, 0);
        acc[rt][gt] = __builtin_amdgcn_mfma_f32_16x16x32_bf16(xa[rt], wlo, acc[rt][gt], 0, 0, 0);
      }
    }
  }
  #pragma unroll
  for (int gt = 0; gt < 4; ++gt) {
    const int col = (wv << 6) + (gt << 4) + l15;
    const float bias = BCL[col];
    #pragma unroll
    for (int rt = 0; rt < 2; ++rt) {
      #pragma unroll
      for (int reg = 0; reg < 4; ++reg) {
        const int row = r0 + rt * 16 + (kg << 2) + reg;
        PREh[(size_t)row * 512 + col] = f2h(acc[rt][gt][reg] + bias);
      }
    }
  }
}

// ---------------- MFMA recurrent hh LSTM layer ----------------
__device__ __forceinline__ float cellf(float4 g, float& c) {
  const float ig = 1.f / (1.f + __expf(-g.x));
  const float fg = 1.f / (1.f + __expf(-g.y));
  const float gg = tanhf(g.z);
  const float og = 1.f / (1.f + __expf(-g.w));
  c = fmaf(fg, c, ig * gg);
  return og * tanhf(c);
}

__global__ __launch_bounds__(512)
void rec2_kernel(const unsigned short* __restrict__ PREh,
                 const unsigned short* __restrict__ PHHB,
                 unsigned short* __restrict__ HOUTu)
{
  __shared__ unsigned short whi[65536];        // [kc4][gt32][lane64][e8] = 128 KB
  __shared__ unsigned short afr[2][4][64][8];  // [split][kc][lane][e]   = 8 KB
  const int tid = threadIdx.x;
  const int lane = tid & 63;
  const int w = tid >> 6;                      // 0..7: gates [w*64, w*64+64)
  const int l15 = lane & 15;
  const int kg = lane >> 4;
  const int q0 = blockIdx.x << 4;
  for (int i = tid; i < 8192; i += 512)
    reinterpret_cast<uint4*>(whi)[i] = reinterpret_cast<const uint4*>(PHHB)[i];
  reinterpret_cast<uint4*>(&afr[0][0][0][0])[tid] = make_uint4(0u, 0u, 0u, 0u);
  const unsigned short* wloG = PHHB + 65536;
  float cs[4] = {0.f, 0.f, 0.f, 0.f};
  const int qq = l15 & 3;
  const int uu = l15 >> 2;
  const int seq = (kg << 2) + qq;
  for (int t = 0; t < 16; ++t) {
    __syncthreads();
    bf16x8 ah[4], al[4];
    #pragma unroll
    for (int kc = 0; kc < 4; ++kc) {
      ah[kc] = *reinterpret_cast<const bf16x8*>(&afr[0][kc][lane][0]);
      al[kc] = *reinterpret_cast<const bf16x8*>(&afr[1][kc][lane][0]);
    }
    f32x4 acc[4];
    #pragma unroll
    for (int gl = 0; gl < 4; ++gl)
      #pragma unroll
      for (int e = 0; e < 4; ++e) acc[gl][e] = 0.f;
    #pragma unroll
    for (int gl = 0; gl < 4; ++gl) {
      const int gt = (w << 2) + gl;
      #pragma unroll
      for (int kc = 0; kc < 4; ++kc) {
        const int off = ((kc * 32 + gt) * 64 + lane) * 8;
        bf16x8 wh = *reinterpret_cast<const bf16x8*>(&whi[off]);
        bf16x8 wl = *reinterpret_cast<const bf16x8*>(&wloG[off]);
        acc[gl] = __builtin_amdgcn_mfma_f32_16x16x32_bf16(ah[kc], wh, acc[gl], 0, 0, 0);
        acc[gl] = __builtin_amdgcn_mfma_f32_16x16x32_bf16(ah[kc], wl, acc[gl], 0, 0, 0);
        acc[gl] = __builtin_amdgcn_mfma_f32_16x16x32_bf16(al[kc], wh, acc[gl], 0, 0, 0);
      }
    }
    __syncthreads();
    const int row = ((q0 + seq) << 4) + t;
    #pragma unroll
    for (int gl = 0; gl < 4; ++gl) {
      const int gt = (w << 2) + gl;
      float in0 = acc[gl][0], in1 = acc[gl][1], in2 = acc[gl][2], in3 = acc[gl][3];
      float s0 = __shfl_xor(in1, 1), s1 = __shfl_xor(in0, 1),
            s2 = __shfl_xor(in3, 1), s3 = __shfl_xor(in2, 1);
      const bool b0 = (qq & 1);
      float t0 = b0 ? s0 : in0;
      float t1 = b0 ? in1 : s1;
      float t2 = b0 ? s2 : in2;
      float t3 = b0 ? in3 : s3;
      float u0 = __shfl_xor(t2, 2), u1 = __shfl_xor(t3, 2),
            u2 = __shfl_xor(t0, 2), u3 = __shfl_xor(t1, 2);
      const bool b1 = (qq & 2);
      float g0 = b1 ? u0 : t0;
      float g1 = b1 ? u1 : t1;
      float g2 = b1 ? t2 : u2;
      float g3 = b1 ? t3 : u3;
      const unsigned short* pp = PREh + (size_t)row * 512 + (gt << 4) + (uu << 2);
      ushort4 pu = *reinterpret_cast<const ushort4*>(pp);
      float4 gv = make_float4(g0 + h2f(pu.x), g1 + h2f(pu.y),
                              g2 + h2f(pu.z), g3 + h2f(pu.w));
      float h = cellf(gv, cs[gl]);
      const int unit = (gt << 2) + uu;
      unsigned short hh = f2bf(h);
      HOUTu[(size_t)row * 128 + unit] = hh;
      if (t < 15) {
        unsigned short hl = f2bf(h - bf2f(hh));
        const int kc2 = unit >> 5;
        const int lane2 = seq | (((unit & 31) >> 3) << 4);
        const int e2 = unit & 7;
        afr[0][kc2][lane2][e2] = hh;
        afr[1][kc2][lane2][e2] = hl;
      }
    }
  }
}

// ---------------- attention pool + skip MLP + head ----------------
__global__ __launch_bounds__(64)
void attn_kernel(const unsigned short* __restrict__ LOu, const float* __restrict__ X,
                 const float* __restrict__ Wa, const float* __restrict__ ba,
                 const float* __restrict__ bs1, const float* __restrict__ bs2,
                 const float* __restrict__ bh1, const float* __restrict__ bh2,
                 const float* __restrict__ Wh2, const float* __restrict__ HWT,
                 float* __restrict__ out)
{
  const int q = blockIdx.x, l = threadIdx.x;
  const unsigned short* lob = LOu + (size_t)q * 2048;
  float loa[16], lobv[16];
  #pragma unroll
  for (int t = 0; t < 16; ++t) {
    loa[t]  = bf2f(lob[t * 128 + l]);
    lobv[t] = bf2f(lob[t * 128 + 64 + l]);
  }
  const float wa = Wa[l], wb = Wa[64 + l];
  float sc[16];
  #pragma unroll
  for (int t = 0; t < 16; ++t) sc[t] = rsum64(loa[t] * wa + lobv[t] * wb) + ba[0];
  float mx = sc[0];
  #pragma unroll
  for (int t = 1; t < 16; ++t) mx = fmaxf(mx, sc[t]);
  float den = 0.f;
  #pragma unroll
  for (int t = 0; t < 16; ++t) { sc[t] = __expf(sc[t] - mx); den += sc[t]; }
  const float inv = 1.f / den;
  float ca = 0.f, cb = 0.f;
  #pragma unroll
  for (int t = 0; t < 16; ++t) {
    float wgt = sc[t] * inv;
    ca = fmaf(wgt, loa[t], ca);
    cb = fmaf(wgt, lobv[t], cb);
  }
  __shared__ float zsh[160];
  __shared__ float hsk[64];
  __shared__ float skin[16];
  zsh[l] = ca; zsh[64 + l] = cb;
  const int bb = q / 1000, nn = q - bb * 1000;
  if (l < 13) skin[l] = X[(size_t)((bb * 16 + 15) * 1000 + nn) * 32 + l];
  __syncthreads();
  float h1 = bs1[l];
  for (int c = 0; c < 13; ++c) h1 = fmaf(skin[c], HWT[c * 64 + l], h1);
  h1 = geluf(h1);
  hsk[l] = h1;
  __syncthreads();
  if (l < 32) {
    float a = bs2[l];
    for (int jj = 0; jj < 64; ++jj) a = fmaf(hsk[jj], HWT[832 + jj * 32 + l], a);
    zsh[128 + l] = a;
  }
  __syncthreads();
  float hh = bh1[l];
  for (int r = 0; r < 160; ++r) hh = fmaf(zsh[r], HWT[2880 + r * 64 + l], hh);
  hh = geluf(hh);
  float s = rsum64(hh * Wh2[l]);
  if (l == 0) out[q] = s + bh2[0];
}

// ---------------- launch ----------------
extern "C" void kernel_launch(void* const* d_in, const int* in_sizes, int n_in,
                              void* d_out, int out_size, void* d_ws, size_t ws_size,
                              hipStream_t stream)
{
  const float* x    = (const float*)d_in[0];
  const int*   ei   = (const int*)d_in[1];
  const float* Wp   = (const float*)d_in[2];
  const float* bp   = (const float*)d_in[3];
  const float* Wl1  = (const float*)d_in[4];
  const float* Wr1  = (const float*)d_in[5];
  const float* a1   = (const float*)d_in[6];
  const float* bg1  = (const float*)d_in[7];
  const float* g1   = (const float*)d_in[8];
  const float* be1  = (const float*)d_in[9];
  const float* m1   = (const float*)d_in[10];
  const float* v1   = (const float*)d_in[11];
  const float* Wl2  = (const float*)d_in[12];
  const float* Wr2  = (const float*)d_in[13];
  const float* a2   = (const float*)d_in[14];
  const float* bg2  = (const float*)d_in[15];
  const float* g2   = (const float*)d_in[16];
  const float* be2  = (const float*)d_in[17];
  const float* m2   = (const float*)d_in[18];
  const float* v2   = (const float*)d_in[19];
  const float* Wih0 = (const float*)d_in[20];
  const float* Whh0 = (const float*)d_in[21];
  const float* bih0 = (const float*)d_in[22];
  const float* bhh0 = (const float*)d_in[23];
  const float* Wih1 = (const float*)d_in[24];
  const float* Whh1 = (const float*)d_in[25];
  const float* bih1 = (const float*)d_in[26];
  const float* bhh1 = (const float*)d_in[27];
  const float* Wa   = (const float*)d_in[28];
  const float* ba   = (const float*)d_in[29];
  const float* Ws1  = (const float*)d_in[30];
  const float* bs1  = (const float*)d_in[31];
  const float* Ws2  = (const float*)d_in[32];
  const float* bs2  = (const float*)d_in[33];
  const float* Wh1  = (const float*)d_in[34];
  const float* bh1  = (const float*)d_in[35];
  const float* Wh2  = (const float*)d_in[36];
  const float* bh2  = (const float*)d_in[37];

  float* ws = (float*)d_ws;
  int* srcD   = (int*)(ws + O_SRCD);
  int* dstD   = (int*)(ws + O_DSTD);
  int* counts = (int*)(ws + O_COUNTS);
  int* offs   = (int*)(ws + O_OFFS);
  int* curs   = (int*)(ws + O_CURS);
  int* esrc   = (int*)(ws + O_EPAD);
  float* PW1  = ws + O_PW1;
  unsigned short* PW2Bu = (unsigned short*)(ws + O_PW2);          // 131072 bf16
  unsigned short* PHHBu = (unsigned short*)(ws + O_LW);           // 262144 bf16
  unsigned short* PWBu  = (unsigned short*)(ws + O_LW + 131072u); // 262144 bf16
  float* BC   = ws + O_BCOMB;
  float* ABF  = ws + O_ABF;
  float* HWT  = ws + O_HWT;
  unsigned short* XL1u = (unsigned short*)(ws + O_BIG0);          // fp16
  unsigned short* XR1u = (unsigned short*)(ws + O_BIG1);
  unsigned short* H1u  = (unsigned short*)(ws + O_BIG2);
  unsigned short* XPu  = (unsigned short*)(ws + O_BIG3);
  unsigned short* Hresu = (unsigned short*)(ws + O_BIG4);
  unsigned short* XL2u = (unsigned short*)(ws + O_BIG0);          // fp16
  unsigned short* XR2u = (unsigned short*)(ws + O_BIG0 + 8192000u);
  unsigned short* PREh = (unsigned short*)(ws + O_BIG0);
  unsigned short* H1SEQu = (unsigned short*)(ws + O_BIG2);
  unsigned short* LOu  = (unsigned short*)(ws + O_BIG3);
  float* SXL1 = ws + O_SXL;               // [64][1001][2] (pre-scaled 0.6*log2e, sentinel row 1000)
  float* SXL2 = ws + O_SXL2;              // [64][1001]
  float* C1F  = ws + O_C1F;               // [2][32]
  float* C2F  = ws + O_C2F;               // [256]
  float* outp = (float*)d_out;

  prep_edges<<<95, 256, 0, stream>>>(ei, srcD, dstD, counts, esrc);
  hist_kernel<<<67, 256, 0, stream>>>(dstD, counts);
  scan_kernel<<<1, 1024, 0, stream>>>(counts, offs, curs);
  fill_kernel<<<67, 256, 0, stream>>>(srcD, dstD, curs, esrc);
  pack_kernel<<<1024, 256, 0, stream>>>(Wl1, Wr1, Wp, Wl2, Wr2,
      Wih0, Whh0, bih0, bhh0, Wih1, Whh1, bih1, bhh1,
      g1, be1, m1, v1, bg1, g2, be2, m2, v2, bg2,
      Ws1, Ws2, Wh1, a1, a2, PW1, PW2Bu, PHHBu, PWBu, BC, ABF, HWT, C1F, C2F,
      SXL1, SXL2);
  proj1_kernel<<<4000, 320, 0, stream>>>(x, PW1, bp, C1F, XL1u, XR1u, XPu, SXL1);
  gat1_kernel<<<dim3(250, 64), 256, 0, stream>>>(XL1u, XR1u, SXL1, esrc, offs, a1, ABF,
                                                 C2F, H1u, SXL2);
  proj2_kernel<<<2000, 512, 0, stream>>>(H1u, PW2Bu, XL2u, XR2u);
  gat2_kernel<<<dim3(250, 64), 256, 0, stream>>>(XL2u, XR2u, SXL2, esrc, offs, a2, ABF,
                                                 XPu, Hresu);
  gemm_pre_kernel<<<2000, 512, 0, stream>>>(Hresu, PWBu, BC, PREh);
  rec2_kernel<<<250, 512, 0, stream>>>(PREh, PHHBu, H1SEQu);
  gemm_pre_kernel<<<2000, 512, 0, stream>>>(H1SEQu, PWBu + 131072u, BC + 512, PREh);
  rec2_kernel<<<250, 512, 0, stream>>>(PREh, PHHBu + 131072u, LOu);
  attn_kernel<<<4000, 64, 0, stream>>>(LOu, x, Wa, ba, bs1, bs2, bh1, bh2, Wh2, HWT, outp);
}

// Round 21
// 456.416 us; speedup vs baseline: 1.0024x; 1.0024x over previous
//
#include <hip/hip_runtime.h>
#include <hip/hip_fp16.h>

#define EPS_BN 1e-5f
#define LOG2E 1.4426950408889634f

typedef __attribute__((ext_vector_type(8))) short bf16x8;
typedef __attribute__((ext_vector_type(4))) float f32x4;
typedef _Float16 h2 __attribute__((ext_vector_type(2)));

#if defined(__has_builtin)
#if __has_builtin(__builtin_amdgcn_fdot2)
#define HAVE_FDOT2 1
#endif
#endif

// ---------------- workspace layout (float-unit offsets) ----------------
#define O_SRCD   0u
#define O_DSTD   17024u
#define O_COUNTS 34048u
#define O_OFFS   35072u
#define O_CURS   36096u
#define O_EIDX   37120u                    // esrc (src node id, CSR-ordered)
#define O_PW1    54144u                    // [32][640]  (Wl1T|Wr1T|WpT)
#define O_PW2    74624u                    // PW2B: 131072 bf16 B-frags (Wl2|Wr2)
#define O_LW     140160u                   // PHHB (262144 bf16) + PWB (262144 bf16)
#define O_BCOMB  402304u                   // [2][128j][4]  (gp order)
#define O_ABF    403328u                   // A1(256)|B1(256)|A2(128)|B2(128)
#define O_HWT    404352u                   // Ws1T(832)|Ws2T(2048)|Wh1T(10240)
#define O_BIG0   417536u                   // XL1(fp16) | XL2(fp16) | PRE(fp16)
#define O_BIG1   (O_BIG0 + 16384000u)      // XR1(bf16) | XR2(bf16 at +8192000)
#define O_BIG2   (O_BIG1 + 16384000u)      // H1(bf16)  | h1seq(bf16)
#define O_BIG3   (O_BIG2 + 16384000u)      // XP(bf16)  | LO(bf16)
#define O_BIG4   (O_BIG3 + 8192000u)       // Hres(bf16)
#define O_SXL    (O_BIG4 + 8192000u)       // SXL1 (128000) | SXL2 (64000) | C1F(64) | C2F(256)

__device__ __forceinline__ float rsum32(float p) {
  p += __shfl_xor(p, 1);  p += __shfl_xor(p, 2);  p += __shfl_xor(p, 4);
  p += __shfl_xor(p, 8);  p += __shfl_xor(p, 16); return p;
}
__device__ __forceinline__ float rsum64(float p) {
  p = rsum32(p); p += __shfl_xor(p, 32); return p;
}
__device__ __forceinline__ float eluf(float x)  { return x > 0.f ? x : expm1f(x); }
__device__ __forceinline__ float geluf(float x) { return 0.5f * x * (1.f + erff(x * 0.70710678118654752f)); }
__device__ __forceinline__ unsigned short f2bf(float f) {
  unsigned int u = __float_as_uint(f);
  u += 0x7FFFu + ((u >> 16) & 1u);
  return (unsigned short)(u >> 16);
}
__device__ __forceinline__ float bf2f(unsigned short h) {
  return __uint_as_float(((unsigned int)h) << 16);
}
__device__ __forceinline__ unsigned short f2h(float x) {
  __half h = __float2half(x);
  return *reinterpret_cast<unsigned short*>(&h);
}
__device__ __forceinline__ float h2f(unsigned short u) {
  __half h = *reinterpret_cast<__half*>(&u);
  return __half2float(h);
}
__device__ __forceinline__ void unpk(unsigned int w, float& lo, float& hi) {
  lo = __uint_as_float(w << 16);
  hi = __uint_as_float(w & 0xFFFF0000u);
}
__device__ __forceinline__ void unpk8(uint4 u, float (&x)[8]) {
  unpk(u.x, x[0], x[1]); unpk(u.y, x[2], x[3]);
  unpk(u.z, x[4], x[5]); unpk(u.w, x[6], x[7]);
}
__device__ __forceinline__ h2 h2bits(unsigned int w) {
  return *reinterpret_cast<h2*>(&w);
}
__device__ __forceinline__ unsigned int bitsh2(h2 v) {
  return *reinterpret_cast<unsigned int*>(&v);
}
__device__ __forceinline__ h2 habs2v(h2 v) {
  unsigned int u = bitsh2(v) & 0x7FFF7FFFu;
  return h2bits(u);
}
__device__ __forceinline__ float dot2f(h2 a, h2 b, float c) {
#ifdef HAVE_FDOT2
  return __builtin_amdgcn_fdot2(a, b, c, false);
#else
  return fmaf((float)a[1], (float)b[1], fmaf((float)a[0], (float)b[0], c));
#endif
}
// packed logit: sum_k a_k * |x_k + xr_k| over 8 features (a pre-scaled by 0.4*log2e)
__device__ __forceinline__ float gat_logit(uint4 u, const h2* xrh, const h2* avh) {
  float p = 0.f;
  p = dot2f(habs2v(h2bits(u.x) + xrh[0]), avh[0], p);
  p = dot2f(habs2v(h2bits(u.y) + xrh[1]), avh[1], p);
  p = dot2f(habs2v(h2bits(u.z) + xrh[2]), avh[2], p);
  p = dot2f(habs2v(h2bits(u.w) + xrh[3]), avh[3], p);
  return p;
}

// ---------------- prep kernels (parallel, 4 small) ----------------
__global__ void prep_edges(const int* __restrict__ ei, int* __restrict__ srcD,
                           int* __restrict__ dstD, int* __restrict__ counts) {
  int i = blockIdx.x * 256 + threadIdx.x;
  if (i < 1024) counts[i] = 0;
  if (i < 17000) {
    int s = (i < 16000) ? ei[i] : (i - 16000);
    int d = (i < 16000) ? ei[16000 + i] : (i - 16000);
    srcD[i] = s; dstD[i] = d;
  }
}
__global__ void hist_kernel(const int* __restrict__ dstD, int* __restrict__ counts) {
  int i = blockIdx.x * 256 + threadIdx.x;
  if (i < 17000) atomicAdd(&counts[dstD[i]], 1);
}
__global__ void scan_kernel(const int* __restrict__ counts, int* __restrict__ offs,
                            int* __restrict__ curs) {
  __shared__ int sh[1024];
  int i = threadIdx.x;
  int v = (i < 1000) ? counts[i] : 0;
  sh[i] = v;
  __syncthreads();
  for (int d = 1; d < 1024; d <<= 1) {
    int t = (i >= d) ? sh[i - d] : 0;
    __syncthreads();
    sh[i] += t;
    __syncthreads();
  }
  if (i < 1000) { offs[i + 1] = sh[i]; curs[i] = sh[i] - v; }
  if (i == 0) offs[0] = 0;
}
__global__ void fill_kernel(const int* __restrict__ srcD, const int* __restrict__ dstD,
                            int* __restrict__ curs, int* __restrict__ esrc) {
  int i = blockIdx.x * 256 + threadIdx.x;
  if (i < 17000) { int p = atomicAdd(&curs[dstD[i]], 1); esrc[p] = srcD[i]; }
}

// PHHB/PWB: hh/ih weights split-bf16 MFMA B-frags [L][split][kc4][gt32][lane64][e8]
// PW2B: GAT2 proj weights split-bf16 B-frags [sp][kc8][ct16][lane64][e8]
// C1F/C2F pre-scaled by 0.6*log2e
__global__ void pack_kernel(
    const float* __restrict__ Wl1, const float* __restrict__ Wr1, const float* __restrict__ Wp,
    const float* __restrict__ Wl2, const float* __restrict__ Wr2,
    const float* __restrict__ Wih0, const float* __restrict__ Whh0,
    const float* __restrict__ bih0, const float* __restrict__ bhh0,
    const float* __restrict__ Wih1, const float* __restrict__ Whh1,
    const float* __restrict__ bih1, const float* __restrict__ bhh1,
    const float* __restrict__ g1, const float* __restrict__ be1, const float* __restrict__ m1,
    const float* __restrict__ v1, const float* __restrict__ bg1,
    const float* __restrict__ g2, const float* __restrict__ be2, const float* __restrict__ m2,
    const float* __restrict__ v2, const float* __restrict__ bg2,
    const float* __restrict__ Ws1, const float* __restrict__ Ws2, const float* __restrict__ Wh1,
    const float* __restrict__ a1, const float* __restrict__ a2,
    float* __restrict__ PW1, unsigned short* __restrict__ PW2Bu,
    unsigned short* __restrict__ PHHBu, unsigned short* __restrict__ PWBu,
    float* __restrict__ BC, float* __restrict__ ABF, float* __restrict__ HWT,
    float* __restrict__ C1F, float* __restrict__ C2F)
{
  int i = blockIdx.x * 256 + threadIdx.x;
  if (i < 262144) {  // PHHB + PWB split-bf16
    int e = i & 7, lane = (i >> 3) & 63, gt = (i >> 9) & 31,
        kc = (i >> 14) & 3, sp = (i >> 16) & 1, L = (i >> 17) & 1;
    int gp = (gt << 4) + (lane & 15);
    int jj = gp >> 2, gate = gp & 3;
    int kk = (kc << 5) + ((lane >> 4) << 3) + e;
    const float* Wih = L ? Wih1 : Wih0;
    const float* Whh = L ? Whh1 : Whh0;
    float wv = Wih[(gate * 128 + jj) * 128 + kk];
    unsigned short hi = f2bf(wv);
    PWBu[i] = (sp == 0) ? hi : f2bf(wv - bf2f(hi));
    float hv = Whh[(gate * 128 + jj) * 128 + kk];
    unsigned short hhi = f2bf(hv);
    PHHBu[i] = (sp == 0) ? hhi : f2bf(hv - bf2f(hhi));
  }
  if (i < 131072) {  // PW2B split-bf16 B-frags
    int e = i & 7, lane = (i >> 3) & 63, ct = (i >> 9) & 15,
        kc = (i >> 13) & 7, sp = (i >> 16) & 1;
    int c = (ct << 4) + (lane & 15);
    int k = (kc << 5) + ((lane >> 4) << 3) + e;
    float wv2 = (c < 128) ? Wl2[c * 256 + k] : Wr2[(c - 128) * 256 + k];
    unsigned short hi = f2bf(wv2);
    PW2Bu[i] = (sp == 0) ? hi : f2bf(wv2 - bf2f(hi));
  }
  if (i < 20480) { int g = i % 640, k = i / 640;
    PW1[i] = (g < 256) ? Wl1[g * 32 + k] : (g < 512) ? Wr1[(g - 256) * 32 + k]
                                                     : Wp[(g - 512) * 32 + k]; }
  if (i < 1024) { int u = i & 3, jj = (i >> 2) & 127, L = i >> 9;
    BC[i] = (L ? bih1 : bih0)[u * 128 + jj] + (L ? bhh1 : bhh0)[u * 128 + jj]; }
  if (i < 768) {
    if (i < 256) ABF[i] = g1[i] * rsqrtf(v1[i] + EPS_BN);
    else if (i < 512) { int c = i - 256; float a = g1[c] * rsqrtf(v1[c] + EPS_BN);
      ABF[i] = (bg1[c] - m1[c]) * a + be1[c]; }
    else if (i < 640) { int c = i - 512; ABF[i] = g2[c] * rsqrtf(v2[c] + EPS_BN); }
    else { int c = i - 640; float a = g2[c] * rsqrtf(v2[c] + EPS_BN);
      ABF[i] = (bg2[c] - m2[c]) * a + be2[c]; }
  }
  if (i < 13120) {
    if (i < 832) { int l = i & 63, c = i >> 6; HWT[i] = Ws1[l * 13 + c]; }
    else if (i < 2880) { int k = i - 832; int l = k & 31, jj = k >> 5; HWT[i] = Ws2[l * 64 + jj]; }
    else { int k = i - 2880; int l = k & 63, r = k >> 6; HWT[i] = Wh1[l * 160 + r]; }
  }
  if (i < 64) {   // C1F (pre-scaled 0.6*log2e)
    int k = i & 31, h = i >> 5;
    float s = 0.f;
    for (int j = 0; j < 128; ++j)
      s = fmaf(a1[h * 128 + j], Wl1[(h * 128 + j) * 32 + k], s);
    C1F[i] = 0.6f * LOG2E * s;
  }
  if (i < 256) {  // C2F (pre-scaled 0.6*log2e)
    float s = 0.f;
    for (int c = 0; c < 128; ++c)
      s = fmaf(a2[c], Wl2[c * 256 + i], s);
    C2F[i] = 0.6f * LOG2E * s;
  }
}

// ---------------- projection 1 (+fused slx1): x -> xl1(fp16)|xr1(bf16)|xp(bf16) + SXL1 --
__global__ __launch_bounds__(320)
void proj1_kernel(const float* __restrict__ X, const float* __restrict__ PW1,
                  const float* __restrict__ bp, const float* __restrict__ C1F,
                  unsigned short* __restrict__ XL1u,
                  unsigned short* __restrict__ XR1u, unsigned short* __restrict__ XPu,
                  float* __restrict__ SXL1)
{
  __shared__ __align__(16) float xs[32][16];
  const int tid = threadIdx.x;
  const int r0 = blockIdx.x * 16;
  for (int el = tid; el < 512; el += 320) {
    int r = el >> 5, k = el & 31;
    xs[k][r] = X[(size_t)(r0 + r) * 32 + k];
  }
  __syncthreads();
  if (tid < 32) {                       // slx1 = dot(C1F[h], x_row), pre-scaled 0.6*log2e
    int r = tid & 15, h = tid >> 4;
    const float* c1 = C1F + h * 32;
    float s = 0.f;
    for (int k = 0; k < 32; ++k) s = fmaf(c1[k], xs[k][r], s);
    SXL1[(size_t)(r0 + r) * 2 + h] = s;
  }
  const int gA = tid, gB = tid + 320;
  float accA[16], accB[16];
  const float iB = (gB >= 512) ? bp[gB - 512] : 0.f;
  #pragma unroll
  for (int r = 0; r < 16; ++r) { accA[r] = 0.f; accB[r] = iB; }
  for (int k = 0; k < 32; ++k) {
    float wA = PW1[k * 640 + gA], wB = PW1[k * 640 + gB];
    float xv[16];
    #pragma unroll
    for (int q = 0; q < 4; ++q)
      *reinterpret_cast<float4*>(&xv[q * 4]) = *reinterpret_cast<const float4*>(&xs[k][q * 4]);
    #pragma unroll
    for (int r = 0; r < 16; ++r) {
      accA[r] = fmaf(wA, xv[r], accA[r]);
      accB[r] = fmaf(wB, xv[r], accB[r]);
    }
  }
  for (int r = 0; r < 16; ++r) {
    size_t row = r0 + r;
    if (gA < 256) XL1u[row * 256 + gA] = f2h(accA[r]);        // fp16
    else          XR1u[row * 256 + (gA - 256)] = f2bf(accA[r]);
    if (gB < 512) XR1u[row * 256 + (gB - 256)] = f2bf(accB[r]);
    else          XPu[row * 128 + (gB - 512)] = f2bf(accB[r]);
  }
}

// ---------------- GAT layer 1: packed fp16 math + exp2, 4 edges/wave-iter ----------
__global__ __launch_bounds__(256)
__attribute__((amdgpu_waves_per_eu(4)))
void gat1_kernel(const unsigned short* __restrict__ XLu, const unsigned short* __restrict__ XRu,
                 const float* __restrict__ SXL,
                 const int* __restrict__ esrc, const int* __restrict__ offs,
                 const float* __restrict__ a1, const float* __restrict__ ABF,
                 const float* __restrict__ C2F,
                 unsigned short* __restrict__ H1u, float* __restrict__ SXL2)
{
  const int lane = threadIdx.x & 63;
  const int wv = threadIdx.x >> 6;
  const int n = blockIdx.x * 4 + wv;
  const int b = blockIdx.y;
  const int epar = lane >> 5;              // edge parity
  const int head = (lane >> 4) & 1;
  const int li = lane & 15;
  const int f0 = head * 128 + li * 8;
  const int beg = offs[n];
  const int deg = offs[n + 1] - beg;
  const char* XLbase = (const char*)XLu + (size_t)b * 512000u;   // 1000 rows * 512 B
  const float* SXLb = SXL + (size_t)b * 2000;
  const unsigned fb = (unsigned)(f0 * 2);
  h2 xrh[4], avh[4];
  {
    const uint4* xrp = reinterpret_cast<const uint4*>(XRu + (size_t)(b * 1000 + n) * 256 + f0);
    float xr[8]; unpk8(xrp[0], xr);
    const float* ap = a1 + f0;
    float4 a0 = *reinterpret_cast<const float4*>(ap);
    float4 a1v = *reinterpret_cast<const float4*>(ap + 4);
    float av[8] = {a0.x, a0.y, a0.z, a0.w, a1v.x, a1v.y, a1v.z, a1v.w};
    const float asc = 0.4f * LOG2E;
    #pragma unroll
    for (int k = 0; k < 4; ++k) {
      h2 t; t[0] = (_Float16)xr[2 * k]; t[1] = (_Float16)xr[2 * k + 1]; xrh[k] = t;
      h2 s; s[0] = (_Float16)(av[2 * k] * asc); s[1] = (_Float16)(av[2 * k + 1] * asc); avh[k] = s;
    }
  }
  float ssum = 0.f;
  h2 acch[4];
  #pragma unroll
  for (int k = 0; k < 4; ++k) { h2 z; z[0] = (_Float16)0.f; z[1] = (_Float16)0.f; acch[k] = z; }
  // slots A (edge i0+epar) and B (edge i0+2+epar), step 4
  int iA = epar, iB = 2 + epar;
  bool vA = iA < deg, vB = iB < deg;
  unsigned sA = (unsigned)esrc[beg + (vA ? iA : 0)];
  unsigned sB = (unsigned)esrc[beg + (vB ? iB : 0)];
  uint4 uA = *reinterpret_cast<const uint4*>(XLbase + (size_t)((sA << 9) + fb));
  uint4 uB = *reinterpret_cast<const uint4*>(XLbase + (size_t)((sB << 9) + fb));
  float slA = vA ? SXLb[sA * 2 + head] : -1e30f;
  float slB = vB ? SXLb[sB * 2 + head] : -1e30f;
  for (int i0 = 0; i0 < deg; i0 += 4) {
    int nA = i0 + 4 + epar, nB = i0 + 6 + epar;
    bool nvA = nA < deg, nvB = nB < deg;
    unsigned tA = (unsigned)esrc[beg + (nvA ? nA : 0)];
    unsigned tB = (unsigned)esrc[beg + (nvB ? nB : 0)];
    uint4 puA = *reinterpret_cast<const uint4*>(XLbase + (size_t)((tA << 9) + fb));
    uint4 puB = *reinterpret_cast<const uint4*>(XLbase + (size_t)((tB << 9) + fb));
    float pslA = nvA ? SXLb[tA * 2 + head] : -1e30f;
    float pslB = nvB ? SXLb[tB * 2 + head] : -1e30f;
    float pA = gat_logit(uA, xrh, avh);
    float pB = gat_logit(uB, xrh, avh);
    pA += __shfl_xor(pA, 1); pB += __shfl_xor(pB, 1);
    pA += __shfl_xor(pA, 2); pB += __shfl_xor(pB, 2);
    pA += __shfl_xor(pA, 4); pB += __shfl_xor(pB, 4);
    pA += __shfl_xor(pA, 8); pB += __shfl_xor(pB, 8);
    float weA = exp2f(pA + slA);           // slA=-1e30 when invalid -> 0
    float weB = exp2f(pB + slB);
    ssum += weA + weB;
    h2 wA2; wA2[0] = (_Float16)weA; wA2[1] = wA2[0];
    h2 wB2; wB2[0] = (_Float16)weB; wB2[1] = wB2[0];
    acch[0] = wA2 * h2bits(uA.x) + acch[0];
    acch[1] = wA2 * h2bits(uA.y) + acch[1];
    acch[2] = wA2 * h2bits(uA.z) + acch[2];
    acch[3] = wA2 * h2bits(uA.w) + acch[3];
    acch[0] = wB2 * h2bits(uB.x) + acch[0];
    acch[1] = wB2 * h2bits(uB.y) + acch[1];
    acch[2] = wB2 * h2bits(uB.z) + acch[2];
    acch[3] = wB2 * h2bits(uB.w) + acch[3];
    uA = puA; uB = puB; slA = pslA; slB = pslB;
  }
  // merge edge-parity halves (same head): lane ^ 32
  ssum += __shfl_xor(ssum, 32);
  float inv = 1.f / ssum;
  float acc[8];
  #pragma unroll
  for (int k = 0; k < 4; ++k) {
    unsigned ob = (unsigned)__shfl_xor((int)bitsh2(acch[k]), 32);
    h2 m = acch[k] + h2bits(ob);
    acc[2 * k] = (float)m[0];
    acc[2 * k + 1] = (float)m[1];
  }
  float A4[8], B4[8];
  {
    const float* aap = ABF + f0;
    float4 t0 = *reinterpret_cast<const float4*>(aap);
    float4 t1 = *reinterpret_cast<const float4*>(aap + 4);
    A4[0]=t0.x; A4[1]=t0.y; A4[2]=t0.z; A4[3]=t0.w;
    A4[4]=t1.x; A4[5]=t1.y; A4[6]=t1.z; A4[7]=t1.w;
    const float* bbp = ABF + 256 + f0;
    float4 s0v = *reinterpret_cast<const float4*>(bbp);
    float4 s1v = *reinterpret_cast<const float4*>(bbp + 4);
    B4[0]=s0v.x; B4[1]=s0v.y; B4[2]=s0v.z; B4[3]=s0v.w;
    B4[4]=s1v.x; B4[5]=s1v.y; B4[6]=s1v.z; B4[7]=s1v.w;
  }
  float o[8];
  #pragma unroll
  for (int k = 0; k < 8; ++k)
    o[k] = eluf(fmaf(acc[k] * inv, A4[k], B4[k]));
  // fused slx2 = dot(C2F, H1row) (pre-scaled 0.6*log2e)
  {
    const float* cp = C2F + f0;
    float4 c0 = *reinterpret_cast<const float4*>(cp);
    float4 c1 = *reinterpret_cast<const float4*>(cp + 4);
    float cc[8] = {c0.x, c0.y, c0.z, c0.w, c1.x, c1.y, c1.z, c1.w};
    float s2 = 0.f;
    #pragma unroll
    for (int k = 0; k < 8; ++k) s2 = fmaf(cc[k], o[k], s2);
    s2 += __shfl_xor(s2, 1); s2 += __shfl_xor(s2, 2);
    s2 += __shfl_xor(s2, 4); s2 += __shfl_xor(s2, 8);
    s2 += __shfl_xor(s2, 16);
    if (lane == 0) SXL2[(size_t)b * 1000 + n] = s2;
  }
  if (lane < 32) {
    unsigned short* hp = H1u + (size_t)(b * 1000 + n) * 256 + f0;
    ushort4 w0 = make_ushort4(f2bf(o[0]), f2bf(o[1]), f2bf(o[2]), f2bf(o[3]));
    ushort4 w1 = make_ushort4(f2bf(o[4]), f2bf(o[5]), f2bf(o[6]), f2bf(o[7]));
    *reinterpret_cast<ushort4*>(hp) = w0;
    *reinterpret_cast<ushort4*>(hp + 4) = w1;
  }
}

// ---------------- projection 2 (MFMA, bf16 A direct): h1 -> xl2(fp16)|xr2(bf16) --------
__global__ __launch_bounds__(512)
void proj2_kernel(const unsigned short* __restrict__ H1u, const unsigned short* __restrict__ PW2B,
                  unsigned short* __restrict__ XL2u, unsigned short* __restrict__ XR2u)
{
  const int tid = threadIdx.x;
  const int lane = tid & 63;
  const int wv = tid >> 6;
  const int l15 = lane & 15;
  const int kg = lane >> 4;
  const int r0 = blockIdx.x * 32;
  f32x4 acc[2][2];
  #pragma unroll
  for (int rt = 0; rt < 2; ++rt)
    #pragma unroll
    for (int ct = 0; ct < 2; ++ct)
      #pragma unroll
      for (int e = 0; e < 4; ++e) acc[rt][ct][e] = 0.f;
  for (int kc = 0; kc < 8; ++kc) {
    bf16x8 xa[2];
    #pragma unroll
    for (int rt = 0; rt < 2; ++rt)
      xa[rt] = *reinterpret_cast<const bf16x8*>(
          H1u + (size_t)(r0 + rt * 16 + l15) * 256 + (kc << 5) + (kg << 3));
    #pragma unroll
    for (int ct = 0; ct < 2; ++ct) {
      const int ctg = (wv << 1) + ct;
      const unsigned short* wp = PW2B + ((size_t)(kc * 16 + ctg)) * 512 + lane * 8;
      bf16x8 whi = *reinterpret_cast<const bf16x8*>(wp);
      bf16x8 wlo = *reinterpret_cast<const bf16x8*>(wp + 65536);
      #pragma unroll
      for (int rt = 0; rt < 2; ++rt) {
        acc[rt][ct] = __builtin_amdgcn_mfma_f32_16x16x32_bf16(xa[rt], whi, acc[rt][ct], 0, 0, 0);
        acc[rt][ct] = __builtin_amdgcn_mfma_f32_16x16x32_bf16(xa[rt], wlo, acc[rt][ct], 0, 0, 0);
      }
    }
  }
  #pragma unroll
  for (int ct = 0; ct < 2; ++ct) {
    const int col = (wv << 5) + (ct << 4) + l15;
    #pragma unroll
    for (int rt = 0; rt < 2; ++rt) {
      #pragma unroll
      for (int reg = 0; reg < 4; ++reg) {
        const int row = r0 + rt * 16 + (kg << 2) + reg;
        float val = acc[rt][ct][reg];
        if (col < 128) XL2u[(size_t)row * 128 + col] = f2h(val);   // fp16
        else           XR2u[(size_t)row * 128 + (col - 128)] = f2bf(val);
      }
    }
  }
}

// ---------------- GAT layer 2: packed fp16 math + exp2, 8 edges/wave-iter + residual ---
__global__ __launch_bounds__(256)
__attribute__((amdgpu_waves_per_eu(4)))
void gat2_kernel(const unsigned short* __restrict__ XLu, const unsigned short* __restrict__ XRu,
                 const float* __restrict__ SXL,
                 const int* __restrict__ esrc, const int* __restrict__ offs,
                 const float* __restrict__ a2, const float* __restrict__ ABF,
                 const unsigned short* __restrict__ XPu, unsigned short* __restrict__ Hresu)
{
  const int lane = threadIdx.x & 63;
  const int wv = threadIdx.x >> 6;
  const int n = blockIdx.x * 4 + wv;
  const int b = blockIdx.y;
  const int grp = lane >> 4;               // edge slot 0..3
  const int li = lane & 15;
  const int f0 = li * 8;
  const int beg = offs[n];
  const int deg = offs[n + 1] - beg;
  const char* XLbase = (const char*)XLu + (size_t)b * 256000u;   // 1000 rows * 256 B
  const float* SXLb = SXL + (size_t)b * 1000;
  const unsigned fb = (unsigned)(f0 * 2);
  h2 xrh[4], avh[4];
  {
    const uint4* xrp = reinterpret_cast<const uint4*>(XRu + (size_t)(b * 1000 + n) * 128 + f0);
    float xr[8]; unpk8(xrp[0], xr);
    const float* ap = a2 + f0;
    float4 a0 = *reinterpret_cast<const float4*>(ap);
    float4 a1v = *reinterpret_cast<const float4*>(ap + 4);
    float av[8] = {a0.x, a0.y, a0.z, a0.w, a1v.x, a1v.y, a1v.z, a1v.w};
    const float asc = 0.4f * LOG2E;
    #pragma unroll
    for (int k = 0; k < 4; ++k) {
      h2 t; t[0] = (_Float16)xr[2 * k]; t[1] = (_Float16)xr[2 * k + 1]; xrh[k] = t;
      h2 s; s[0] = (_Float16)(av[2 * k] * asc); s[1] = (_Float16)(av[2 * k + 1] * asc); avh[k] = s;
    }
  }
  float ssum = 0.f;
  h2 acch[4];
  #pragma unroll
  for (int k = 0; k < 4; ++k) { h2 z; z[0] = (_Float16)0.f; z[1] = (_Float16)0.f; acch[k] = z; }
  // slots A (edge i0+grp) and B (edge i0+4+grp), step 8
  int iA = grp, iB = 4 + grp;
  bool vA = iA < deg, vB = iB < deg;
  unsigned sA = (unsigned)esrc[beg + (vA ? iA : 0)];
  unsigned sB = (unsigned)esrc[beg + (vB ? iB : 0)];
  uint4 uA = *reinterpret_cast<const uint4*>(XLbase + (size_t)((sA << 8) + fb));
  uint4 uB = *reinterpret_cast<const uint4*>(XLbase + (size_t)((sB << 8) + fb));
  float slA = vA ? SXLb[sA] : -1e30f;
  float slB = vB ? SXLb[sB] : -1e30f;
  for (int i0 = 0; i0 < deg; i0 += 8) {
    int nA = i0 + 8 + grp, nB = i0 + 12 + grp;
    bool nvA = nA < deg, nvB = nB < deg;
    unsigned tA = (unsigned)esrc[beg + (nvA ? nA : 0)];
    unsigned tB = (unsigned)esrc[beg + (nvB ? nB : 0)];
    uint4 puA = *reinterpret_cast<const uint4*>(XLbase + (size_t)((tA << 8) + fb));
    uint4 puB = *reinterpret_cast<const uint4*>(XLbase + (size_t)((tB << 8) + fb));
    float pslA = nvA ? SXLb[tA] : -1e30f;
    float pslB = nvB ? SXLb[tB] : -1e30f;
    float pA = gat_logit(uA, xrh, avh);
    float pB = gat_logit(uB, xrh, avh);
    pA += __shfl_xor(pA, 1); pB += __shfl_xor(pB, 1);
    pA += __shfl_xor(pA, 2); pB += __shfl_xor(pB, 2);
    pA += __shfl_xor(pA, 4); pB += __shfl_xor(pB, 4);
    pA += __shfl_xor(pA, 8); pB += __shfl_xor(pB, 8);
    float weA = exp2f(pA + slA);
    float weB = exp2f(pB + slB);
    ssum += weA + weB;
    h2 wA2; wA2[0] = (_Float16)weA; wA2[1] = wA2[0];
    h2 wB2; wB2[0] = (_Float16)weB; wB2[1] = wB2[0];
    acch[0] = wA2 * h2bits(uA.x) + acch[0];
    acch[1] = wA2 * h2bits(uA.y) + acch[1];
    acch[2] = wA2 * h2bits(uA.z) + acch[2];
    acch[3] = wA2 * h2bits(uA.w) + acch[3];
    acch[0] = wB2 * h2bits(uB.x) + acch[0];
    acch[1] = wB2 * h2bits(uB.y) + acch[1];
    acch[2] = wB2 * h2bits(uB.z) + acch[2];
    acch[3] = wB2 * h2bits(uB.w) + acch[3];
    uA = puA; uB = puB; slA = pslA; slB = pslB;
  }
  // merge 4 edge groups: xor16 then xor32 (plain adds, softmax shift cancels)
  ssum += __shfl_xor(ssum, 16);
  ssum += __shfl_xor(ssum, 32);
  float acc[8];
  #pragma unroll
  for (int k = 0; k < 4; ++k) {
    unsigned o16 = (unsigned)__shfl_xor((int)bitsh2(acch[k]), 16);
    h2 m = acch[k] + h2bits(o16);
    unsigned o32 = (unsigned)__shfl_xor((int)bitsh2(m), 32);
    m = m + h2bits(o32);
    acc[2 * k] = (float)m[0];
    acc[2 * k + 1] = (float)m[1];
  }
  float inv = 1.f / ssum;
  if (lane < 16) {
    const float* aap = ABF + 512 + f0;
    float4 t0 = *reinterpret_cast<const float4*>(aap);
    float4 t1 = *reinterpret_cast<const float4*>(aap + 4);
    const float* bbp = ABF + 640 + f0;
    float4 s0v = *reinterpret_cast<const float4*>(bbp);
    float4 s1v = *reinterpret_cast<const float4*>(bbp + 4);
    float xp8[8];
    unpk8(*reinterpret_cast<const uint4*>(XPu + (size_t)(b * 1000 + n) * 128 + f0), xp8);
    float A4[8] = {t0.x, t0.y, t0.z, t0.w, t1.x, t1.y, t1.z, t1.w};
    float B4[8] = {s0v.x, s0v.y, s0v.z, s0v.w, s1v.x, s1v.y, s1v.z, s1v.w};
    unsigned short* hp = Hresu + (size_t)(b * 1000 + n) * 128 + f0;
    ushort4 w0, w1;
    w0.x = f2bf(eluf(fmaf(acc[0] * inv, A4[0], B4[0])) + xp8[0]);
    w0.y = f2bf(eluf(fmaf(acc[1] * inv, A4[1], B4[1])) + xp8[1]);
    w0.z = f2bf(eluf(fmaf(acc[2] * inv, A4[2], B4[2])) + xp8[2]);
    w0.w = f2bf(eluf(fmaf(acc[3] * inv, A4[3], B4[3])) + xp8[3]);
    w1.x = f2bf(eluf(fmaf(acc[4] * inv, A4[4], B4[4])) + xp8[4]);
    w1.y = f2bf(eluf(fmaf(acc[5] * inv, A4[5], B4[5])) + xp8[5]);
    w1.z = f2bf(eluf(fmaf(acc[6] * inv, A4[6], B4[6])) + xp8[6]);
    w1.w = f2bf(eluf(fmaf(acc[7] * inv, A4[7], B4[7])) + xp8[7]);
    *reinterpret_cast<ushort4*>(hp) = w0;
    *reinterpret_cast<ushort4*>(hp + 4) = w1;
  }
}

// ---------------- MFMA pre-GEMM (bf16 A direct): PRE = fp16( X @ WihT + BC ) ----------
__global__ __launch_bounds__(512)
void gemm_pre_kernel(const unsigned short* __restrict__ Xu, const unsigned short* __restrict__ PWB,
                     const float* __restrict__ BCL, unsigned short* __restrict__ PREh)
{
  const int tid = threadIdx.x;
  const int lane = tid & 63;
  const int wv = tid >> 6;
  const int l15 = lane & 15;
  const int kg = lane >> 4;
  const int r0 = blockIdx.x * 32;
  f32x4 acc[2][4];
  #pragma unroll
  for (int rt = 0; rt < 2; ++rt)
    #pragma unroll
    for (int gt = 0; gt < 4; ++gt)
      #pragma unroll
      for (int e = 0; e < 4; ++e) acc[rt][gt][e] = 0.f;
  for (int kc = 0; kc < 4; ++kc) {
    bf16x8 xa[2];
    #pragma unroll
    for (int rt = 0; rt < 2; ++rt)
      xa[rt] = *reinterpret_cast<const bf16x8*>(
          Xu + (size_t)(r0 + rt * 16 + l15) * 128 + (kc << 5) + (kg << 3));
    #pragma unroll
    for (int gt = 0; gt < 4; ++gt) {
      const int gtg = (wv << 2) + gt;
      const unsigned short* wp = PWB + ((size_t)(kc * 32 + gtg)) * 512 + lane * 8;
      bf16x8 whi = *reinterpret_cast<const bf16x8*>(wp);
      bf16x8 wlo = *reinterpret_cast<const bf16x8*>(wp + 65536);
      #pragma unroll
      for (int rt = 0; rt < 2; ++rt) {
        acc[rt][gt] = __builtin_amdgcn_mfma_f32_16x16x32_bf16(xa[rt], whi, acc[rt][gt], 0, 0, 0);
        acc[rt][gt] = __builtin_amdgcn_mfma_f32_16x16x32_bf16(xa[rt], wlo, acc[rt][gt], 0, 0, 0);
      }
    }
  }
  #pragma unroll
  for (int gt = 0; gt < 4; ++gt) {
    const int col = (wv << 6) + (gt << 4) + l15;
    const float bias = BCL[col];
    #pragma unroll
    for (int rt = 0; rt < 2; ++rt) {
      #pragma unroll
      for (int reg = 0; reg < 4; ++reg) {
        const int row = r0 + rt * 16 + (kg << 2) + reg;
        PREh[(size_t)row * 512 + col] = f2h(acc[rt][gt][reg] + bias);
      }
    }
  }
}

// ---------------- MFMA recurrent hh LSTM layer ----------------
__device__ __forceinline__ float cellf(float4 g, float& c) {
  const float ig = 1.f / (1.f + __expf(-g.x));
  const float fg = 1.f / (1.f + __expf(-g.y));
  const float gg = tanhf(g.z);
  const float og = 1.f / (1.f + __expf(-g.w));
  c = fmaf(fg, c, ig * gg);
  return og * tanhf(c);
}

__global__ __launch_bounds__(512)
void rec2_kernel(const unsigned short* __restrict__ PREh,
                 const unsigned short* __restrict__ PHHB,
                 unsigned short* __restrict__ HOUTu)
{
  __shared__ unsigned short whi[65536];        // [kc4][gt32][lane64][e8] = 128 KB
  __shared__ unsigned short afr[2][4][64][8];  // [split][kc][lane][e]   = 8 KB
  const int tid = threadIdx.x;
  const int lane = tid & 63;
  const int w = tid >> 6;                      // 0..7: gates [w*64, w*64+64)
  const int l15 = lane & 15;
  const int kg = lane >> 4;
  const int q0 = blockIdx.x << 4;
  for (int i = tid; i < 8192; i += 512)
    reinterpret_cast<uint4*>(whi)[i] = reinterpret_cast<const uint4*>(PHHB)[i];
  reinterpret_cast<uint4*>(&afr[0][0][0][0])[tid] = make_uint4(0u, 0u, 0u, 0u);
  const unsigned short* wloG = PHHB + 65536;
  float cs[4] = {0.f, 0.f, 0.f, 0.f};
  const int qq = l15 & 3;
  const int uu = l15 >> 2;
  const int seq = (kg << 2) + qq;
  for (int t = 0; t < 16; ++t) {
    __syncthreads();
    bf16x8 ah[4], al[4];
    #pragma unroll
    for (int kc = 0; kc < 4; ++kc) {
      ah[kc] = *reinterpret_cast<const bf16x8*>(&afr[0][kc][lane][0]);
      al[kc] = *reinterpret_cast<const bf16x8*>(&afr[1][kc][lane][0]);
    }
    f32x4 acc[4];
    #pragma unroll
    for (int gl = 0; gl < 4; ++gl)
      #pragma unroll
      for (int e = 0; e < 4; ++e) acc[gl][e] = 0.f;
    #pragma unroll
    for (int gl = 0; gl < 4; ++gl) {
      const int gt = (w << 2) + gl;
      #pragma unroll
      for (int kc = 0; kc < 4; ++kc) {
        const int off = ((kc * 32 + gt) * 64 + lane) * 8;
        bf16x8 wh = *reinterpret_cast<const bf16x8*>(&whi[off]);
        bf16x8 wl = *reinterpret_cast<const bf16x8*>(&wloG[off]);
        acc[gl] = __builtin_amdgcn_mfma_f32_16x16x32_bf16(ah[kc], wh, acc[gl], 0, 0, 0);
        acc[gl] = __builtin_amdgcn_mfma_f32_16x16x32_bf16(ah[kc], wl, acc[gl], 0, 0, 0);
        acc[gl] = __builtin_amdgcn_mfma_f32_16x16x32_bf16(al[kc], wh, acc[gl], 0, 0, 0);
      }
    }
    __syncthreads();
    const int row = ((q0 + seq) << 4) + t;
    #pragma unroll
    for (int gl = 0; gl < 4; ++gl) {
      const int gt = (w << 2) + gl;
      float in0 = acc[gl][0], in1 = acc[gl][1], in2 = acc[gl][2], in3 = acc[gl][3];
      float s0 = __shfl_xor(in1, 1), s1 = __shfl_xor(in0, 1),
            s2 = __shfl_xor(in3, 1), s3 = __shfl_xor(in2, 1);
      const bool b0 = (qq & 1);
      float t0 = b0 ? s0 : in0;
      float t1 = b0 ? in1 : s1;
      float t2 = b0 ? s2 : in2;
      float t3 = b0 ? in3 : s3;
      float u0 = __shfl_xor(t2, 2), u1 = __shfl_xor(t3, 2),
            u2 = __shfl_xor(t0, 2), u3 = __shfl_xor(t1, 2);
      const bool b1 = (qq & 2);
      float g0 = b1 ? u0 : t0;
      float g1 = b1 ? u1 : t1;
      float g2 = b1 ? t2 : u2;
      float g3 = b1 ? t3 : u3;
      const unsigned short* pp = PREh + (size_t)row * 512 + (gt << 4) + (uu << 2);
      ushort4 pu = *reinterpret_cast<const ushort4*>(pp);
      float4 gv = make_float4(g0 + h2f(pu.x), g1 + h2f(pu.y),
                              g2 + h2f(pu.z), g3 + h2f(pu.w));
      float h = cellf(gv, cs[gl]);
      const int unit = (gt << 2) + uu;
      unsigned short hh = f2bf(h);
      HOUTu[(size_t)row * 128 + unit] = hh;
      if (t < 15) {
        unsigned short hl = f2bf(h - bf2f(hh));
        const int kc2 = unit >> 5;
        const int lane2 = seq | (((unit & 31) >> 3) << 4);
        const int e2 = unit & 7;
        afr[0][kc2][lane2][e2] = hh;
        afr[1][kc2][lane2][e2] = hl;
      }
    }
  }
}

// ---------------- attention pool + skip MLP + head ----------------
__global__ __launch_bounds__(64)
void attn_kernel(const unsigned short* __restrict__ LOu, const float* __restrict__ X,
                 const float* __restrict__ Wa, const float* __restrict__ ba,
                 const float* __restrict__ bs1, const float* __restrict__ bs2,
                 const float* __restrict__ bh1, const float* __restrict__ bh2,
                 const float* __restrict__ Wh2, const float* __restrict__ HWT,
                 float* __restrict__ out)
{
  const int q = blockIdx.x, l = threadIdx.x;
  const unsigned short* lob = LOu + (size_t)q * 2048;
  float loa[16], lobv[16];
  #pragma unroll
  for (int t = 0; t < 16; ++t) {
    loa[t]  = bf2f(lob[t * 128 + l]);
    lobv[t] = bf2f(lob[t * 128 + 64 + l]);
  }
  const float wa = Wa[l], wb = Wa[64 + l];
  float sc[16];
  #pragma unroll
  for (int t = 0; t < 16; ++t) sc[t] = rsum64(loa[t] * wa + lobv[t] * wb) + ba[0];
  float mx = sc[0];
  #pragma unroll
  for (int t = 1; t < 16; ++t) mx = fmaxf(mx, sc[t]);
  float den = 0.f;
  #pragma unroll
  for (int t = 0; t < 16; ++t) { sc[t] = __expf(sc[t] - mx); den += sc[t]; }
  const float inv = 1.f / den;
  float ca = 0.f, cb = 0.f;
  #pragma unroll
  for (int t = 0; t < 16; ++t) {
    float wgt = sc[t] * inv;
    ca = fmaf(wgt, loa[t], ca);
    cb = fmaf(wgt, lobv[t], cb);
  }
  __shared__ float zsh[160];
  __shared__ float hsk[64];
  __shared__ float skin[16];
  zsh[l] = ca; zsh[64 + l] = cb;
  const int bb = q / 1000, nn = q - bb * 1000;
  if (l < 13) skin[l] = X[(size_t)((bb * 16 + 15) * 1000 + nn) * 32 + l];
  __syncthreads();
  float h1 = bs1[l];
  for (int c = 0; c < 13; ++c) h1 = fmaf(skin[c], HWT[c * 64 + l], h1);
  h1 = geluf(h1);
  hsk[l] = h1;
  __syncthreads();
  if (l < 32) {
    float a = bs2[l];
    for (int jj = 0; jj < 64; ++jj) a = fmaf(hsk[jj], HWT[832 + jj * 32 + l], a);
    zsh[128 + l] = a;
  }
  __syncthreads();
  float hh = bh1[l];
  for (int r = 0; r < 160; ++r) hh = fmaf(zsh[r], HWT[2880 + r * 64 + l], hh);
  hh = geluf(hh);
  float s = rsum64(hh * Wh2[l]);
  if (l == 0) out[q] = s + bh2[0];
}

// ---------------- launch ----------------
extern "C" void kernel_launch(void* const* d_in, const int* in_sizes, int n_in,
                              void* d_out, int out_size, void* d_ws, size_t ws_size,
                              hipStream_t stream)
{
  const float* x    = (const float*)d_in[0];
  const int*   ei   = (const int*)d_in[1];
  const float* Wp   = (const float*)d_in[2];
  const float* bp   = (const float*)d_in[3];
  const float* Wl1  = (const float*)d_in[4];
  const float* Wr1  = (const float*)d_in[5];
  const float* a1   = (const float*)d_in[6];
  const float* bg1  = (const float*)d_in[7];
  const float* g1   = (const float*)d_in[8];
  const float* be1  = (const float*)d_in[9];
  const float* m1   = (const float*)d_in[10];
  const float* v1   = (const float*)d_in[11];
  const float* Wl2  = (const float*)d_in[12];
  const float* Wr2  = (const float*)d_in[13];
  const float* a2   = (const float*)d_in[14];
  const float* bg2  = (const float*)d_in[15];
  const float* g2   = (const float*)d_in[16];
  const float* be2  = (const float*)d_in[17];
  const float* m2   = (const float*)d_in[18];
  const float* v2   = (const float*)d_in[19];
  const float* Wih0 = (const float*)d_in[20];
  const float* Whh0 = (const float*)d_in[21];
  const float* bih0 = (const float*)d_in[22];
  const float* bhh0 = (const float*)d_in[23];
  const float* Wih1 = (const float*)d_in[24];
  const float* Whh1 = (const float*)d_in[25];
  const float* bih1 = (const float*)d_in[26];
  const float* bhh1 = (const float*)d_in[27];
  const float* Wa   = (const float*)d_in[28];
  const float* ba   = (const float*)d_in[29];
  const float* Ws1  = (const float*)d_in[30];
  const float* bs1  = (const float*)d_in[31];
  const float* Ws2  = (const float*)d_in[32];
  const float* bs2  = (const float*)d_in[33];
  const float* Wh1  = (const float*)d_in[34];
  const float* bh1  = (const float*)d_in[35];
  const float* Wh2  = (const float*)d_in[36];
  const float* bh2  = (const float*)d_in[37];

  float* ws = (float*)d_ws;
  int* srcD   = (int*)(ws + O_SRCD);
  int* dstD   = (int*)(ws + O_DSTD);
  int* counts = (int*)(ws + O_COUNTS);
  int* offs   = (int*)(ws + O_OFFS);
  int* curs   = (int*)(ws + O_CURS);
  int* esrc   = (int*)(ws + O_EIDX);
  float* PW1  = ws + O_PW1;
  unsigned short* PW2Bu = (unsigned short*)(ws + O_PW2);          // 131072 bf16
  unsigned short* PHHBu = (unsigned short*)(ws + O_LW);           // 262144 bf16
  unsigned short* PWBu  = (unsigned short*)(ws + O_LW + 131072u); // 262144 bf16
  float* BC   = ws + O_BCOMB;
  float* ABF  = ws + O_ABF;
  float* HWT  = ws + O_HWT;
  unsigned short* XL1u = (unsigned short*)(ws + O_BIG0);          // fp16
  unsigned short* XR1u = (unsigned short*)(ws + O_BIG1);
  unsigned short* H1u  = (unsigned short*)(ws + O_BIG2);
  unsigned short* XPu  = (unsigned short*)(ws + O_BIG3);
  unsigned short* Hresu = (unsigned short*)(ws + O_BIG4);
  unsigned short* XL2u = (unsigned short*)(ws + O_BIG0);          // fp16
  unsigned short* XR2u = (unsigned short*)(ws + O_BIG0 + 8192000u);
  unsigned short* PREh = (unsigned short*)(ws + O_BIG0);
  unsigned short* H1SEQu = (unsigned short*)(ws + O_BIG2);
  unsigned short* LOu  = (unsigned short*)(ws + O_BIG3);
  float* SXL1 = ws + O_SXL;               // [64000][2] (pre-scaled by 0.6*log2e)
  float* SXL2 = ws + O_SXL + 128000u;     // [64000]    (pre-scaled by 0.6*log2e)
  float* C1F  = ws + O_SXL + 192000u;     // [2][32]
  float* C2F  = ws + O_SXL + 192064u;     // [256]
  float* outp = (float*)d_out;

  prep_edges<<<67, 256, 0, stream>>>(ei, srcD, dstD, counts);
  hist_kernel<<<67, 256, 0, stream>>>(dstD, counts);
  scan_kernel<<<1, 1024, 0, stream>>>(counts, offs, curs);
  fill_kernel<<<67, 256, 0, stream>>>(srcD, dstD, curs, esrc);
  pack_kernel<<<1024, 256, 0, stream>>>(Wl1, Wr1, Wp, Wl2, Wr2,
      Wih0, Whh0, bih0, bhh0, Wih1, Whh1, bih1, bhh1,
      g1, be1, m1, v1, bg1, g2, be2, m2, v2, bg2,
      Ws1, Ws2, Wh1, a1, a2, PW1, PW2Bu, PHHBu, PWBu, BC, ABF, HWT, C1F, C2F);
  proj1_kernel<<<4000, 320, 0, stream>>>(x, PW1, bp, C1F, XL1u, XR1u, XPu, SXL1);
  gat1_kernel<<<dim3(250, 64), 256, 0, stream>>>(XL1u, XR1u, SXL1, esrc, offs, a1, ABF,
                                                 C2F, H1u, SXL2);
  proj2_kernel<<<2000, 512, 0, stream>>>(H1u, PW2Bu, XL2u, XR2u);
  gat2_kernel<<<dim3(250, 64), 256, 0, stream>>>(XL2u, XR2u, SXL2, esrc, offs, a2, ABF,
                                                 XPu, Hresu);
  gemm_pre_kernel<<<2000, 512, 0, stream>>>(Hresu, PWBu, BC, PREh);
  rec2_kernel<<<250, 512, 0, stream>>>(PREh, PHHBu, H1SEQu);
  gemm_pre_kernel<<<2000, 512, 0, stream>>>(H1SEQu, PWBu + 131072u, BC + 512, PREh);
  rec2_kernel<<<250, 512, 0, stream>>>(PREh, PHHBu + 131072u, LOu);
  attn_kernel<<<4000, 64, 0, stream>>>(LOu, x, Wa, ba, bs1, bs2, bh1, bh2, Wh2, HWT, outp);
}

// Round 22
// 452.698 us; speedup vs baseline: 1.0106x; 1.0082x over previous
//
#include <hip/hip_runtime.h>
#include <hip/hip_fp16.h>

#define EPS_BN 1e-5f

typedef __attribute__((ext_vector_type(8))) short bf16x8;
typedef __attribute__((ext_vector_type(4))) float f32x4;
typedef _Float16 h2 __attribute__((ext_vector_type(2)));

#if defined(__has_builtin)
#if __has_builtin(__builtin_amdgcn_fdot2)
#define HAVE_FDOT2 1
#endif
#endif

// ---------------- workspace layout (float-unit offsets) ----------------
#define O_SRCD   0u
#define O_DSTD   17024u
#define O_COUNTS 34048u
#define O_OFFS   35072u
#define O_CURS   36096u
#define O_EIDX   37120u                    // esrc (src node id, CSR-ordered)
#define O_PW1    54144u                    // [32][640]  (Wl1T|Wr1T|WpT)
#define O_PW2    74624u                    // PW2B: 131072 bf16 B-frags (Wl2|Wr2)
#define O_LW     140160u                   // PHHB (262144 bf16) + PWB (262144 bf16)
#define O_BCOMB  402304u                   // [2][128j][4]  (gp order)
#define O_ABF    403328u                   // A1(256)|B1(256)|A2(128)|B2(128)
#define O_HWT    404352u                   // Ws1T(832)|Ws2T(2048)|Wh1T(10240)
#define O_BIG0   417536u                   // XL1(fp16) | XL2(fp16) | PRE(fp16)
#define O_BIG1   (O_BIG0 + 16384000u)      // XR1(bf16) | XR2(bf16 at +8192000)
#define O_BIG2   (O_BIG1 + 16384000u)      // H1(bf16)  | h1seq(bf16)
#define O_BIG3   (O_BIG2 + 16384000u)      // XP(bf16)  | LO(bf16)
#define O_BIG4   (O_BIG3 + 8192000u)       // Hres(bf16)
#define O_SXL    (O_BIG4 + 8192000u)       // SXL1 (128000) | SXL2 (64000) | C1F(64) | C2F(256)

__device__ __forceinline__ float rsum32(float p) {
  p += __shfl_xor(p, 1);  p += __shfl_xor(p, 2);  p += __shfl_xor(p, 4);
  p += __shfl_xor(p, 8);  p += __shfl_xor(p, 16); return p;
}
__device__ __forceinline__ float rsum64(float p) {
  p = rsum32(p); p += __shfl_xor(p, 32); return p;
}
__device__ __forceinline__ float eluf(float x)  { return x > 0.f ? x : expm1f(x); }
__device__ __forceinline__ float geluf(float x) { return 0.5f * x * (1.f + erff(x * 0.70710678118654752f)); }
__device__ __forceinline__ unsigned short f2bf(float f) {
  unsigned int u = __float_as_uint(f);
  u += 0x7FFFu + ((u >> 16) & 1u);
  return (unsigned short)(u >> 16);
}
__device__ __forceinline__ float bf2f(unsigned short h) {
  return __uint_as_float(((unsigned int)h) << 16);
}
__device__ __forceinline__ unsigned short f2h(float x) {
  __half h = __float2half(x);
  return *reinterpret_cast<unsigned short*>(&h);
}
__device__ __forceinline__ float h2f(unsigned short u) {
  __half h = *reinterpret_cast<__half*>(&u);
  return __half2float(h);
}
__device__ __forceinline__ void unpk(unsigned int w, float& lo, float& hi) {
  lo = __uint_as_float(w << 16);
  hi = __uint_as_float(w & 0xFFFF0000u);
}
__device__ __forceinline__ void unpk8(uint4 u, float (&x)[8]) {
  unpk(u.x, x[0], x[1]); unpk(u.y, x[2], x[3]);
  unpk(u.z, x[4], x[5]); unpk(u.w, x[6], x[7]);
}
__device__ __forceinline__ h2 h2bits(unsigned int w) {
  return *reinterpret_cast<h2*>(&w);
}
__device__ __forceinline__ unsigned int bitsh2(h2 v) {
  return *reinterpret_cast<unsigned int*>(&v);
}
__device__ __forceinline__ h2 habs2v(h2 v) {
  unsigned int u = bitsh2(v) & 0x7FFF7FFFu;
  return h2bits(u);
}
__device__ __forceinline__ float dot2f(h2 a, h2 b, float c) {
#ifdef HAVE_FDOT2
  return __builtin_amdgcn_fdot2(a, b, c, false);
#else
  return fmaf((float)a[1], (float)b[1], fmaf((float)a[0], (float)b[0], c));
#endif
}
// packed logit: sum_k a_k * |x_k + xr_k| over 8 features (4 h2 words)
__device__ __forceinline__ float gat_logit(uint4 u, const h2* xrh, const h2* avh) {
  float p = 0.f;
  p = dot2f(habs2v(h2bits(u.x) + xrh[0]), avh[0], p);
  p = dot2f(habs2v(h2bits(u.y) + xrh[1]), avh[1], p);
  p = dot2f(habs2v(h2bits(u.z) + xrh[2]), avh[2], p);
  p = dot2f(habs2v(h2bits(u.w) + xrh[3]), avh[3], p);
  return p;
}

// ---------------- prep kernels (parallel, 4 small) ----------------
__global__ void prep_edges(const int* __restrict__ ei, int* __restrict__ srcD,
                           int* __restrict__ dstD, int* __restrict__ counts) {
  int i = blockIdx.x * 256 + threadIdx.x;
  if (i < 1024) counts[i] = 0;
  if (i < 17000) {
    int s = (i < 16000) ? ei[i] : (i - 16000);
    int d = (i < 16000) ? ei[16000 + i] : (i - 16000);
    srcD[i] = s; dstD[i] = d;
  }
}
__global__ void hist_kernel(const int* __restrict__ dstD, int* __restrict__ counts) {
  int i = blockIdx.x * 256 + threadIdx.x;
  if (i < 17000) atomicAdd(&counts[dstD[i]], 1);
}
__global__ void scan_kernel(const int* __restrict__ counts, int* __restrict__ offs,
                            int* __restrict__ curs) {
  __shared__ int sh[1024];
  int i = threadIdx.x;
  int v = (i < 1000) ? counts[i] : 0;
  sh[i] = v;
  __syncthreads();
  for (int d = 1; d < 1024; d <<= 1) {
    int t = (i >= d) ? sh[i - d] : 0;
    __syncthreads();
    sh[i] += t;
    __syncthreads();
  }
  if (i < 1000) { offs[i + 1] = sh[i]; curs[i] = sh[i] - v; }
  if (i == 0) offs[0] = 0;
}
__global__ void fill_kernel(const int* __restrict__ srcD, const int* __restrict__ dstD,
                            int* __restrict__ curs, int* __restrict__ esrc) {
  int i = blockIdx.x * 256 + threadIdx.x;
  if (i < 17000) { int p = atomicAdd(&curs[dstD[i]], 1); esrc[p] = srcD[i]; }
}

// PHHB/PWB: hh/ih weights split-bf16 MFMA B-frags [L][split][kc4][gt32][lane64][e8]
// PW2B: GAT2 proj weights split-bf16 B-frags [sp][kc8][ct16][lane64][e8]
// C1F[h*32+k] = 0.6*sum_j a1[h*128+j]*Wl1[(h*128+j)*32+k]; C2F[k] = 0.6*sum_c a2[c]*Wl2[c*256+k]
__global__ void pack_kernel(
    const float* __restrict__ Wl1, const float* __restrict__ Wr1, const float* __restrict__ Wp,
    const float* __restrict__ Wl2, const float* __restrict__ Wr2,
    const float* __restrict__ Wih0, const float* __restrict__ Whh0,
    const float* __restrict__ bih0, const float* __restrict__ bhh0,
    const float* __restrict__ Wih1, const float* __restrict__ Whh1,
    const float* __restrict__ bih1, const float* __restrict__ bhh1,
    const float* __restrict__ g1, const float* __restrict__ be1, const float* __restrict__ m1,
    const float* __restrict__ v1, const float* __restrict__ bg1,
    const float* __restrict__ g2, const float* __restrict__ be2, const float* __restrict__ m2,
    const float* __restrict__ v2, const float* __restrict__ bg2,
    const float* __restrict__ Ws1, const float* __restrict__ Ws2, const float* __restrict__ Wh1,
    const float* __restrict__ a1, const float* __restrict__ a2,
    float* __restrict__ PW1, unsigned short* __restrict__ PW2Bu,
    unsigned short* __restrict__ PHHBu, unsigned short* __restrict__ PWBu,
    float* __restrict__ BC, float* __restrict__ ABF, float* __restrict__ HWT,
    float* __restrict__ C1F, float* __restrict__ C2F)
{
  int i = blockIdx.x * 256 + threadIdx.x;
  if (i < 262144) {  // PHHB + PWB split-bf16
    int e = i & 7, lane = (i >> 3) & 63, gt = (i >> 9) & 31,
        kc = (i >> 14) & 3, sp = (i >> 16) & 1, L = (i >> 17) & 1;
    int gp = (gt << 4) + (lane & 15);
    int jj = gp >> 2, gate = gp & 3;
    int kk = (kc << 5) + ((lane >> 4) << 3) + e;
    const float* Wih = L ? Wih1 : Wih0;
    const float* Whh = L ? Whh1 : Whh0;
    float wv = Wih[(gate * 128 + jj) * 128 + kk];
    unsigned short hi = f2bf(wv);
    PWBu[i] = (sp == 0) ? hi : f2bf(wv - bf2f(hi));
    float hv = Whh[(gate * 128 + jj) * 128 + kk];
    unsigned short hhi = f2bf(hv);
    PHHBu[i] = (sp == 0) ? hhi : f2bf(hv - bf2f(hhi));
  }
  if (i < 131072) {  // PW2B split-bf16 B-frags
    int e = i & 7, lane = (i >> 3) & 63, ct = (i >> 9) & 15,
        kc = (i >> 13) & 7, sp = (i >> 16) & 1;
    int c = (ct << 4) + (lane & 15);
    int k = (kc << 5) + ((lane >> 4) << 3) + e;
    float wv2 = (c < 128) ? Wl2[c * 256 + k] : Wr2[(c - 128) * 256 + k];
    unsigned short hi = f2bf(wv2);
    PW2Bu[i] = (sp == 0) ? hi : f2bf(wv2 - bf2f(hi));
  }
  if (i < 20480) { int g = i % 640, k = i / 640;
    PW1[i] = (g < 256) ? Wl1[g * 32 + k] : (g < 512) ? Wr1[(g - 256) * 32 + k]
                                                     : Wp[(g - 512) * 32 + k]; }
  if (i < 1024) { int u = i & 3, jj = (i >> 2) & 127, L = i >> 9;
    BC[i] = (L ? bih1 : bih0)[u * 128 + jj] + (L ? bhh1 : bhh0)[u * 128 + jj]; }
  if (i < 768) {
    if (i < 256) ABF[i] = g1[i] * rsqrtf(v1[i] + EPS_BN);
    else if (i < 512) { int c = i - 256; float a = g1[c] * rsqrtf(v1[c] + EPS_BN);
      ABF[i] = (bg1[c] - m1[c]) * a + be1[c]; }
    else if (i < 640) { int c = i - 512; ABF[i] = g2[c] * rsqrtf(v2[c] + EPS_BN); }
    else { int c = i - 640; float a = g2[c] * rsqrtf(v2[c] + EPS_BN);
      ABF[i] = (bg2[c] - m2[c]) * a + be2[c]; }
  }
  if (i < 13120) {
    if (i < 832) { int l = i & 63, c = i >> 6; HWT[i] = Ws1[l * 13 + c]; }
    else if (i < 2880) { int k = i - 832; int l = k & 31, jj = k >> 5; HWT[i] = Ws2[l * 64 + jj]; }
    else { int k = i - 2880; int l = k & 63, r = k >> 6; HWT[i] = Wh1[l * 160 + r]; }
  }
  if (i < 64) {   // C1F
    int k = i & 31, h = i >> 5;
    float s = 0.f;
    for (int j = 0; j < 128; ++j)
      s = fmaf(a1[h * 128 + j], Wl1[(h * 128 + j) * 32 + k], s);
    C1F[i] = 0.6f * s;
  }
  if (i < 256) {  // C2F
    float s = 0.f;
    for (int c = 0; c < 128; ++c)
      s = fmaf(a2[c], Wl2[c * 256 + i], s);
    C2F[i] = 0.6f * s;
  }
}

// ---------------- projection 1 (+fused slx1): x -> xl1(fp16)|xr1(bf16)|xp(bf16) + SXL1 --
__global__ __launch_bounds__(320)
void proj1_kernel(const float* __restrict__ X, const float* __restrict__ PW1,
                  const float* __restrict__ bp, const float* __restrict__ C1F,
                  unsigned short* __restrict__ XL1u,
                  unsigned short* __restrict__ XR1u, unsigned short* __restrict__ XPu,
                  float* __restrict__ SXL1)
{
  __shared__ __align__(16) float xs[32][16];
  const int tid = threadIdx.x;
  const int r0 = blockIdx.x * 16;
  for (int el = tid; el < 512; el += 320) {
    int r = el >> 5, k = el & 31;
    xs[k][r] = X[(size_t)(r0 + r) * 32 + k];
  }
  __syncthreads();
  if (tid < 32) {                       // slx1 = dot(C1F[h], x_row), pre-scaled 0.6
    int r = tid & 15, h = tid >> 4;
    const float* c1 = C1F + h * 32;
    float s = 0.f;
    for (int k = 0; k < 32; ++k) s = fmaf(c1[k], xs[k][r], s);
    SXL1[(size_t)(r0 + r) * 2 + h] = s;
  }
  const int gA = tid, gB = tid + 320;
  float accA[16], accB[16];
  const float iB = (gB >= 512) ? bp[gB - 512] : 0.f;
  #pragma unroll
  for (int r = 0; r < 16; ++r) { accA[r] = 0.f; accB[r] = iB; }
  for (int k = 0; k < 32; ++k) {
    float wA = PW1[k * 640 + gA], wB = PW1[k * 640 + gB];
    float xv[16];
    #pragma unroll
    for (int q = 0; q < 4; ++q)
      *reinterpret_cast<float4*>(&xv[q * 4]) = *reinterpret_cast<const float4*>(&xs[k][q * 4]);
    #pragma unroll
    for (int r = 0; r < 16; ++r) {
      accA[r] = fmaf(wA, xv[r], accA[r]);
      accB[r] = fmaf(wB, xv[r], accB[r]);
    }
  }
  for (int r = 0; r < 16; ++r) {
    size_t row = r0 + r;
    if (gA < 256) XL1u[row * 256 + gA] = f2h(accA[r]);        // fp16
    else          XR1u[row * 256 + (gA - 256)] = f2bf(accA[r]);
    if (gB < 512) XR1u[row * 256 + (gB - 256)] = f2bf(accB[r]);
    else          XPu[row * 128 + (gB - 512)] = f2bf(accB[r]);
  }
}

// ---------------- GAT layer 1: packed fp16 math, 4 edges/wave-iter ----------
__global__ __launch_bounds__(256)
__attribute__((amdgpu_waves_per_eu(4)))
void gat1_kernel(const unsigned short* __restrict__ XLu, const unsigned short* __restrict__ XRu,
                 const float* __restrict__ SXL,
                 const int* __restrict__ esrc, const int* __restrict__ offs,
                 const float* __restrict__ a1, const float* __restrict__ ABF,
                 const float* __restrict__ C2F,
                 unsigned short* __restrict__ H1u, float* __restrict__ SXL2)
{
  const int lane = threadIdx.x & 63;
  const int wv = threadIdx.x >> 6;
  const int n = blockIdx.x * 4 + wv;
  const int b = blockIdx.y;
  const int epar = lane >> 5;              // edge parity
  const int head = (lane >> 4) & 1;
  const int li = lane & 15;
  const int f0 = head * 128 + li * 8;
  const int beg = offs[n];
  const int deg = offs[n + 1] - beg;
  const char* XLbase = (const char*)XLu + (size_t)b * 512000u;   // 1000 rows * 512 B
  const float* SXLb = SXL + (size_t)b * 2000;
  const unsigned fb = (unsigned)(f0 * 2);
  h2 xrh[4], avh[4];
  {
    const uint4* xrp = reinterpret_cast<const uint4*>(XRu + (size_t)(b * 1000 + n) * 256 + f0);
    float xr[8]; unpk8(xrp[0], xr);
    const float* ap = a1 + f0;
    float4 a0 = *reinterpret_cast<const float4*>(ap);
    float4 a1v = *reinterpret_cast<const float4*>(ap + 4);
    float av[8] = {a0.x, a0.y, a0.z, a0.w, a1v.x, a1v.y, a1v.z, a1v.w};
    #pragma unroll
    for (int k = 0; k < 4; ++k) {
      h2 t; t[0] = (_Float16)xr[2 * k]; t[1] = (_Float16)xr[2 * k + 1]; xrh[k] = t;
      h2 s; s[0] = (_Float16)av[2 * k]; s[1] = (_Float16)av[2 * k + 1]; avh[k] = s;
    }
  }
  float ssum = 0.f;
  h2 acch[4];
  #pragma unroll
  for (int k = 0; k < 4; ++k) { h2 z; z[0] = (_Float16)0.f; z[1] = (_Float16)0.f; acch[k] = z; }
  // slots A (edge i0+epar) and B (edge i0+2+epar), step 4
  int iA = epar, iB = 2 + epar;
  bool vA = iA < deg, vB = iB < deg;
  unsigned sA = (unsigned)esrc[beg + (vA ? iA : 0)];
  unsigned sB = (unsigned)esrc[beg + (vB ? iB : 0)];
  uint4 uA = *reinterpret_cast<const uint4*>(XLbase + (size_t)((sA << 9) + fb));
  uint4 uB = *reinterpret_cast<const uint4*>(XLbase + (size_t)((sB << 9) + fb));
  float slA = vA ? SXLb[sA * 2 + head] : -1e30f;
  float slB = vB ? SXLb[sB * 2 + head] : -1e30f;
  for (int i0 = 0; i0 < deg; i0 += 4) {
    int nA = i0 + 4 + epar, nB = i0 + 6 + epar;
    bool nvA = nA < deg, nvB = nB < deg;
    unsigned tA = (unsigned)esrc[beg + (nvA ? nA : 0)];
    unsigned tB = (unsigned)esrc[beg + (nvB ? nB : 0)];
    uint4 puA = *reinterpret_cast<const uint4*>(XLbase + (size_t)((tA << 9) + fb));
    uint4 puB = *reinterpret_cast<const uint4*>(XLbase + (size_t)((tB << 9) + fb));
    float pslA = nvA ? SXLb[tA * 2 + head] : -1e30f;
    float pslB = nvB ? SXLb[tB * 2 + head] : -1e30f;
    float pA = gat_logit(uA, xrh, avh);
    float pB = gat_logit(uB, xrh, avh);
    pA += __shfl_xor(pA, 1); pB += __shfl_xor(pB, 1);
    pA += __shfl_xor(pA, 2); pB += __shfl_xor(pB, 2);
    pA += __shfl_xor(pA, 4); pB += __shfl_xor(pB, 4);
    pA += __shfl_xor(pA, 8); pB += __shfl_xor(pB, 8);
    float weA = __expf(fmaf(0.4f, pA, slA));   // slA=-1e30 when invalid -> 0
    float weB = __expf(fmaf(0.4f, pB, slB));
    ssum += weA + weB;
    h2 wA2; wA2[0] = (_Float16)weA; wA2[1] = wA2[0];
    h2 wB2; wB2[0] = (_Float16)weB; wB2[1] = wB2[0];
    acch[0] = wA2 * h2bits(uA.x) + acch[0];
    acch[1] = wA2 * h2bits(uA.y) + acch[1];
    acch[2] = wA2 * h2bits(uA.z) + acch[2];
    acch[3] = wA2 * h2bits(uA.w) + acch[3];
    acch[0] = wB2 * h2bits(uB.x) + acch[0];
    acch[1] = wB2 * h2bits(uB.y) + acch[1];
    acch[2] = wB2 * h2bits(uB.z) + acch[2];
    acch[3] = wB2 * h2bits(uB.w) + acch[3];
    uA = puA; uB = puB; slA = pslA; slB = pslB;
  }
  // merge edge-parity halves (same head): lane ^ 32
  ssum += __shfl_xor(ssum, 32);
  float inv = 1.f / ssum;
  float acc[8];
  #pragma unroll
  for (int k = 0; k < 4; ++k) {
    unsigned ob = (unsigned)__shfl_xor((int)bitsh2(acch[k]), 32);
    h2 m = acch[k] + h2bits(ob);
    acc[2 * k] = (float)m[0];
    acc[2 * k + 1] = (float)m[1];
  }
  float A4[8], B4[8];
  {
    const float* aap = ABF + f0;
    float4 t0 = *reinterpret_cast<const float4*>(aap);
    float4 t1 = *reinterpret_cast<const float4*>(aap + 4);
    A4[0]=t0.x; A4[1]=t0.y; A4[2]=t0.z; A4[3]=t0.w;
    A4[4]=t1.x; A4[5]=t1.y; A4[6]=t1.z; A4[7]=t1.w;
    const float* bbp = ABF + 256 + f0;
    float4 s0v = *reinterpret_cast<const float4*>(bbp);
    float4 s1v = *reinterpret_cast<const float4*>(bbp + 4);
    B4[0]=s0v.x; B4[1]=s0v.y; B4[2]=s0v.z; B4[3]=s0v.w;
    B4[4]=s1v.x; B4[5]=s1v.y; B4[6]=s1v.z; B4[7]=s1v.w;
  }
  float o[8];
  #pragma unroll
  for (int k = 0; k < 8; ++k)
    o[k] = eluf(fmaf(acc[k] * inv, A4[k], B4[k]));
  // fused slx2 = dot(C2F, H1row) (pre-scaled 0.6); o identical on lane and lane^32
  {
    const float* cp = C2F + f0;
    float4 c0 = *reinterpret_cast<const float4*>(cp);
    float4 c1 = *reinterpret_cast<const float4*>(cp + 4);
    float cc[8] = {c0.x, c0.y, c0.z, c0.w, c1.x, c1.y, c1.z, c1.w};
    float s2 = 0.f;
    #pragma unroll
    for (int k = 0; k < 8; ++k) s2 = fmaf(cc[k], o[k], s2);
    s2 += __shfl_xor(s2, 1); s2 += __shfl_xor(s2, 2);
    s2 += __shfl_xor(s2, 4); s2 += __shfl_xor(s2, 8);
    s2 += __shfl_xor(s2, 16);
    if (lane == 0) SXL2[(size_t)b * 1000 + n] = s2;
  }
  if (lane < 32) {
    unsigned short* hp = H1u + (size_t)(b * 1000 + n) * 256 + f0;
    ushort4 w0 = make_ushort4(f2bf(o[0]), f2bf(o[1]), f2bf(o[2]), f2bf(o[3]));
    ushort4 w1 = make_ushort4(f2bf(o[4]), f2bf(o[5]), f2bf(o[6]), f2bf(o[7]));
    *reinterpret_cast<ushort4*>(hp) = w0;
    *reinterpret_cast<ushort4*>(hp + 4) = w1;
  }
}

// ---------------- projection 2 (MFMA, bf16 A direct): h1 -> xl2(fp16)|xr2(bf16) --------
__global__ __launch_bounds__(512)
void proj2_kernel(const unsigned short* __restrict__ H1u, const unsigned short* __restrict__ PW2B,
                  unsigned short* __restrict__ XL2u, unsigned short* __restrict__ XR2u)
{
  const int tid = threadIdx.x;
  const int lane = tid & 63;
  const int wv = tid >> 6;
  const int l15 = lane & 15;
  const int kg = lane >> 4;
  const int r0 = blockIdx.x * 32;
  f32x4 acc[2][2];
  #pragma unroll
  for (int rt = 0; rt < 2; ++rt)
    #pragma unroll
    for (int ct = 0; ct < 2; ++ct)
      #pragma unroll
      for (int e = 0; e < 4; ++e) acc[rt][ct][e] = 0.f;
  for (int kc = 0; kc < 8; ++kc) {
    bf16x8 xa[2];
    #pragma unroll
    for (int rt = 0; rt < 2; ++rt)
      xa[rt] = *reinterpret_cast<const bf16x8*>(
          H1u + (size_t)(r0 + rt * 16 + l15) * 256 + (kc << 5) + (kg << 3));
    #pragma unroll
    for (int ct = 0; ct < 2; ++ct) {
      const int ctg = (wv << 1) + ct;
      const unsigned short* wp = PW2B + ((size_t)(kc * 16 + ctg)) * 512 + lane * 8;
      bf16x8 whi = *reinterpret_cast<const bf16x8*>(wp);
      bf16x8 wlo = *reinterpret_cast<const bf16x8*>(wp + 65536);
      #pragma unroll
      for (int rt = 0; rt < 2; ++rt) {
        acc[rt][ct] = __builtin_amdgcn_mfma_f32_16x16x32_bf16(xa[rt], whi, acc[rt][ct], 0, 0, 0);
        acc[rt][ct] = __builtin_amdgcn_mfma_f32_16x16x32_bf16(xa[rt], wlo, acc[rt][ct], 0, 0, 0);
      }
    }
  }
  #pragma unroll
  for (int ct = 0; ct < 2; ++ct) {
    const int col = (wv << 5) + (ct << 4) + l15;
    #pragma unroll
    for (int rt = 0; rt < 2; ++rt) {
      #pragma unroll
      for (int reg = 0; reg < 4; ++reg) {
        const int row = r0 + rt * 16 + (kg << 2) + reg;
        float val = acc[rt][ct][reg];
        if (col < 128) XL2u[(size_t)row * 128 + col] = f2h(val);   // fp16
        else           XR2u[(size_t)row * 128 + (col - 128)] = f2bf(val);
      }
    }
  }
}

// ---------------- GAT layer 2: packed fp16 math, 8 edges/wave-iter + residual ---------
__global__ __launch_bounds__(256)
__attribute__((amdgpu_waves_per_eu(4)))
void gat2_kernel(const unsigned short* __restrict__ XLu, const unsigned short* __restrict__ XRu,
                 const float* __restrict__ SXL,
                 const int* __restrict__ esrc, const int* __restrict__ offs,
                 const float* __restrict__ a2, const float* __restrict__ ABF,
                 const unsigned short* __restrict__ XPu, unsigned short* __restrict__ Hresu)
{
  const int lane = threadIdx.x & 63;
  const int wv = threadIdx.x >> 6;
  const int n = blockIdx.x * 4 + wv;
  const int b = blockIdx.y;
  const int grp = lane >> 4;               // edge slot 0..3
  const int li = lane & 15;
  const int f0 = li * 8;
  const int beg = offs[n];
  const int deg = offs[n + 1] - beg;
  const char* XLbase = (const char*)XLu + (size_t)b * 256000u;   // 1000 rows * 256 B
  const float* SXLb = SXL + (size_t)b * 1000;
  const unsigned fb = (unsigned)(f0 * 2);
  h2 xrh[4], avh[4];
  {
    const uint4* xrp = reinterpret_cast<const uint4*>(XRu + (size_t)(b * 1000 + n) * 128 + f0);
    float xr[8]; unpk8(xrp[0], xr);
    const float* ap = a2 + f0;
    float4 a0 = *reinterpret_cast<const float4*>(ap);
    float4 a1v = *reinterpret_cast<const float4*>(ap + 4);
    float av[8] = {a0.x, a0.y, a0.z, a0.w, a1v.x, a1v.y, a1v.z, a1v.w};
    #pragma unroll
    for (int k = 0; k < 4; ++k) {
      h2 t; t[0] = (_Float16)xr[2 * k]; t[1] = (_Float16)xr[2 * k + 1]; xrh[k] = t;
      h2 s; s[0] = (_Float16)av[2 * k]; s[1] = (_Float16)av[2 * k + 1]; avh[k] = s;
    }
  }
  float ssum = 0.f;
  h2 acch[4];
  #pragma unroll
  for (int k = 0; k < 4; ++k) { h2 z; z[0] = (_Float16)0.f; z[1] = (_Float16)0.f; acch[k] = z; }
  // slots A (edge i0+grp) and B (edge i0+4+grp), step 8
  int iA = grp, iB = 4 + grp;
  bool vA = iA < deg, vB = iB < deg;
  unsigned sA = (unsigned)esrc[beg + (vA ? iA : 0)];
  unsigned sB = (unsigned)esrc[beg + (vB ? iB : 0)];
  uint4 uA = *reinterpret_cast<const uint4*>(XLbase + (size_t)((sA << 8) + fb));
  uint4 uB = *reinterpret_cast<const uint4*>(XLbase + (size_t)((sB << 8) + fb));
  float slA = vA ? SXLb[sA] : -1e30f;
  float slB = vB ? SXLb[sB] : -1e30f;
  for (int i0 = 0; i0 < deg; i0 += 8) {
    int nA = i0 + 8 + grp, nB = i0 + 12 + grp;
    bool nvA = nA < deg, nvB = nB < deg;
    unsigned tA = (unsigned)esrc[beg + (nvA ? nA : 0)];
    unsigned tB = (unsigned)esrc[beg + (nvB ? nB : 0)];
    uint4 puA = *reinterpret_cast<const uint4*>(XLbase + (size_t)((tA << 8) + fb));
    uint4 puB = *reinterpret_cast<const uint4*>(XLbase + (size_t)((tB << 8) + fb));
    float pslA = nvA ? SXLb[tA] : -1e30f;
    float pslB = nvB ? SXLb[tB] : -1e30f;
    float pA = gat_logit(uA, xrh, avh);
    float pB = gat_logit(uB, xrh, avh);
    pA += __shfl_xor(pA, 1); pB += __shfl_xor(pB, 1);
    pA += __shfl_xor(pA, 2); pB += __shfl_xor(pB, 2);
    pA += __shfl_xor(pA, 4); pB += __shfl_xor(pB, 4);
    pA += __shfl_xor(pA, 8); pB += __shfl_xor(pB, 8);
    float weA = __expf(fmaf(0.4f, pA, slA));
    float weB = __expf(fmaf(0.4f, pB, slB));
    ssum += weA + weB;
    h2 wA2; wA2[0] = (_Float16)weA; wA2[1] = wA2[0];
    h2 wB2; wB2[0] = (_Float16)weB; wB2[1] = wB2[0];
    acch[0] = wA2 * h2bits(uA.x) + acch[0];
    acch[1] = wA2 * h2bits(uA.y) + acch[1];
    acch[2] = wA2 * h2bits(uA.z) + acch[2];
    acch[3] = wA2 * h2bits(uA.w) + acch[3];
    acch[0] = wB2 * h2bits(uB.x) + acch[0];
    acch[1] = wB2 * h2bits(uB.y) + acch[1];
    acch[2] = wB2 * h2bits(uB.z) + acch[2];
    acch[3] = wB2 * h2bits(uB.w) + acch[3];
    uA = puA; uB = puB; slA = pslA; slB = pslB;
  }
  // merge 4 edge groups: xor16 then xor32 (plain adds, softmax shift cancels)
  ssum += __shfl_xor(ssum, 16);
  ssum += __shfl_xor(ssum, 32);
  float acc[8];
  #pragma unroll
  for (int k = 0; k < 4; ++k) {
    unsigned o16 = (unsigned)__shfl_xor((int)bitsh2(acch[k]), 16);
    h2 m = acch[k] + h2bits(o16);
    unsigned o32 = (unsigned)__shfl_xor((int)bitsh2(m), 32);
    m = m + h2bits(o32);
    acc[2 * k] = (float)m[0];
    acc[2 * k + 1] = (float)m[1];
  }
  float inv = 1.f / ssum;
  if (lane < 16) {
    const float* aap = ABF + 512 + f0;
    float4 t0 = *reinterpret_cast<const float4*>(aap);
    float4 t1 = *reinterpret_cast<const float4*>(aap + 4);
    const float* bbp = ABF + 640 + f0;
    float4 s0v = *reinterpret_cast<const float4*>(bbp);
    float4 s1v = *reinterpret_cast<const float4*>(bbp + 4);
    float xp8[8];
    unpk8(*reinterpret_cast<const uint4*>(XPu + (size_t)(b * 1000 + n) * 128 + f0), xp8);
    float A4[8] = {t0.x, t0.y, t0.z, t0.w, t1.x, t1.y, t1.z, t1.w};
    float B4[8] = {s0v.x, s0v.y, s0v.z, s0v.w, s1v.x, s1v.y, s1v.z, s1v.w};
    unsigned short* hp = Hresu + (size_t)(b * 1000 + n) * 128 + f0;
    ushort4 w0, w1;
    w0.x = f2bf(eluf(fmaf(acc[0] * inv, A4[0], B4[0])) + xp8[0]);
    w0.y = f2bf(eluf(fmaf(acc[1] * inv, A4[1], B4[1])) + xp8[1]);
    w0.z = f2bf(eluf(fmaf(acc[2] * inv, A4[2], B4[2])) + xp8[2]);
    w0.w = f2bf(eluf(fmaf(acc[3] * inv, A4[3], B4[3])) + xp8[3]);
    w1.x = f2bf(eluf(fmaf(acc[4] * inv, A4[4], B4[4])) + xp8[4]);
    w1.y = f2bf(eluf(fmaf(acc[5] * inv, A4[5], B4[5])) + xp8[5]);
    w1.z = f2bf(eluf(fmaf(acc[6] * inv, A4[6], B4[6])) + xp8[6]);
    w1.w = f2bf(eluf(fmaf(acc[7] * inv, A4[7], B4[7])) + xp8[7]);
    *reinterpret_cast<ushort4*>(hp) = w0;
    *reinterpret_cast<ushort4*>(hp + 4) = w1;
  }
}

// ---------------- MFMA pre-GEMM (bf16 A direct): PRE = fp16( X @ WihT + BC ) ----------
__global__ __launch_bounds__(512)
void gemm_pre_kernel(const unsigned short* __restrict__ Xu, const unsigned short* __restrict__ PWB,
                     const float* __restrict__ BCL, unsigned short* __restrict__ PREh)
{
  const int tid = threadIdx.x;
  const int lane = tid & 63;
  const int wv = tid >> 6;
  const int l15 = lane & 15;
  const int kg = lane >> 4;
  const int r0 = blockIdx.x * 32;
  f32x4 acc[2][4];
  #pragma unroll
  for (int rt = 0; rt < 2; ++rt)
    #pragma unroll
    for (int gt = 0; gt < 4; ++gt)
      #pragma unroll
      for (int e = 0; e < 4; ++e) acc[rt][gt][e] = 0.f;
  for (int kc = 0; kc < 4; ++kc) {
    bf16x8 xa[2];
    #pragma unroll
    for (int rt = 0; rt < 2; ++rt)
      xa[rt] = *reinterpret_cast<const bf16x8*>(
          Xu + (size_t)(r0 + rt * 16 + l15) * 128 + (kc << 5) + (kg << 3));
    #pragma unroll
    for (int gt = 0; gt < 4; ++gt) {
      const int gtg = (wv << 2) + gt;
      const unsigned short* wp = PWB + ((size_t)(kc * 32 + gtg)) * 512 + lane * 8;
      bf16x8 whi = *reinterpret_cast<const bf16x8*>(wp);
      bf16x8 wlo = *reinterpret_cast<const bf16x8*>(wp + 65536);
      #pragma unroll
      for (int rt = 0; rt < 2; ++rt) {
        acc[rt][gt] = __builtin_amdgcn_mfma_f32_16x16x32_bf16(xa[rt], whi, acc[rt][gt], 0, 0, 0);
        acc[rt][gt] = __builtin_amdgcn_mfma_f32_16x16x32_bf16(xa[rt], wlo, acc[rt][gt], 0, 0, 0);
      }
    }
  }
  #pragma unroll
  for (int gt = 0; gt < 4; ++gt) {
    const int col = (wv << 6) + (gt << 4) + l15;
    const float bias = BCL[col];
    #pragma unroll
    for (int rt = 0; rt < 2; ++rt) {
      #pragma unroll
      for (int reg = 0; reg < 4; ++reg) {
        const int row = r0 + rt * 16 + (kg << 2) + reg;
        PREh[(size_t)row * 512 + col] = f2h(acc[rt][gt][reg] + bias);
      }
    }
  }
}

// ---------------- MFMA recurrent hh LSTM layer ----------------
__device__ __forceinline__ float cellf(float4 g, float& c) {
  const float ig = 1.f / (1.f + __expf(-g.x));
  const float fg = 1.f / (1.f + __expf(-g.y));
  const float gg = tanhf(g.z);
  const float og = 1.f / (1.f + __expf(-g.w));
  c = fmaf(fg, c, ig * gg);
  return og * tanhf(c);
}

__global__ __launch_bounds__(512)
void rec2_kernel(const unsigned short* __restrict__ PREh,
                 const unsigned short* __restrict__ PHHB,
                 unsigned short* __restrict__ HOUTu)
{
  __shared__ unsigned short whi[65536];        // [kc4][gt32][lane64][e8] = 128 KB
  __shared__ unsigned short afr[2][4][64][8];  // [split][kc][lane][e]   = 8 KB
  const int tid = threadIdx.x;
  const int lane = tid & 63;
  const int w = tid >> 6;                      // 0..7: gates [w*64, w*64+64)
  const int l15 = lane & 15;
  const int kg = lane >> 4;
  const int q0 = blockIdx.x << 4;
  for (int i = tid; i < 8192; i += 512)
    reinterpret_cast<uint4*>(whi)[i] = reinterpret_cast<const uint4*>(PHHB)[i];
  reinterpret_cast<uint4*>(&afr[0][0][0][0])[tid] = make_uint4(0u, 0u, 0u, 0u);
  const unsigned short* wloG = PHHB + 65536;
  float cs[4] = {0.f, 0.f, 0.f, 0.f};
  const int qq = l15 & 3;
  const int uu = l15 >> 2;
  const int seq = (kg << 2) + qq;
  for (int t = 0; t < 16; ++t) {
    __syncthreads();
    bf16x8 ah[4], al[4];
    #pragma unroll
    for (int kc = 0; kc < 4; ++kc) {
      ah[kc] = *reinterpret_cast<const bf16x8*>(&afr[0][kc][lane][0]);
      al[kc] = *reinterpret_cast<const bf16x8*>(&afr[1][kc][lane][0]);
    }
    f32x4 acc[4];
    #pragma unroll
    for (int gl = 0; gl < 4; ++gl)
      #pragma unroll
      for (int e = 0; e < 4; ++e) acc[gl][e] = 0.f;
    #pragma unroll
    for (int gl = 0; gl < 4; ++gl) {
      const int gt = (w << 2) + gl;
      #pragma unroll
      for (int kc = 0; kc < 4; ++kc) {
        const int off = ((kc * 32 + gt) * 64 + lane) * 8;
        bf16x8 wh = *reinterpret_cast<const bf16x8*>(&whi[off]);
        bf16x8 wl = *reinterpret_cast<const bf16x8*>(&wloG[off]);
        acc[gl] = __builtin_amdgcn_mfma_f32_16x16x32_bf16(ah[kc], wh, acc[gl], 0, 0, 0);
        acc[gl] = __builtin_amdgcn_mfma_f32_16x16x32_bf16(ah[kc], wl, acc[gl], 0, 0, 0);
        acc[gl] = __builtin_amdgcn_mfma_f32_16x16x32_bf16(al[kc], wh, acc[gl], 0, 0, 0);
      }
    }
    __syncthreads();
    const int row = ((q0 + seq) << 4) + t;
    #pragma unroll
    for (int gl = 0; gl < 4; ++gl) {
      const int gt = (w << 2) + gl;
      float in0 = acc[gl][0], in1 = acc[gl][1], in2 = acc[gl][2], in3 = acc[gl][3];
      float s0 = __shfl_xor(in1, 1), s1 = __shfl_xor(in0, 1),
            s2 = __shfl_xor(in3, 1), s3 = __shfl_xor(in2, 1);
      const bool b0 = (qq & 1);
      float t0 = b0 ? s0 : in0;
      float t1 = b0 ? in1 : s1;
      float t2 = b0 ? s2 : in2;
      float t3 = b0 ? in3 : s3;
      float u0 = __shfl_xor(t2, 2), u1 = __shfl_xor(t3, 2),
            u2 = __shfl_xor(t0, 2), u3 = __shfl_xor(t1, 2);
      const bool b1 = (qq & 2);
      float g0 = b1 ? u0 : t0;
      float g1 = b1 ? u1 : t1;
      float g2 = b1 ? t2 : u2;
      float g3 = b1 ? t3 : u3;
      const unsigned short* pp = PREh + (size_t)row * 512 + (gt << 4) + (uu << 2);
      ushort4 pu = *reinterpret_cast<const ushort4*>(pp);
      float4 gv = make_float4(g0 + h2f(pu.x), g1 + h2f(pu.y),
                              g2 + h2f(pu.z), g3 + h2f(pu.w));
      float h = cellf(gv, cs[gl]);
      const int unit = (gt << 2) + uu;
      unsigned short hh = f2bf(h);
      HOUTu[(size_t)row * 128 + unit] = hh;
      if (t < 15) {
        unsigned short hl = f2bf(h - bf2f(hh));
        const int kc2 = unit >> 5;
        const int lane2 = seq | (((unit & 31) >> 3) << 4);
        const int e2 = unit & 7;
        afr[0][kc2][lane2][e2] = hh;
        afr[1][kc2][lane2][e2] = hl;
      }
    }
  }
}

// ---------------- attention pool + skip MLP + head ----------------
__global__ __launch_bounds__(64)
void attn_kernel(const unsigned short* __restrict__ LOu, const float* __restrict__ X,
                 const float* __restrict__ Wa, const float* __restrict__ ba,
                 const float* __restrict__ bs1, const float* __restrict__ bs2,
                 const float* __restrict__ bh1, const float* __restrict__ bh2,
                 const float* __restrict__ Wh2, const float* __restrict__ HWT,
                 float* __restrict__ out)
{
  const int q = blockIdx.x, l = threadIdx.x;
  const unsigned short* lob = LOu + (size_t)q * 2048;
  float loa[16], lobv[16];
  #pragma unroll
  for (int t = 0; t < 16; ++t) {
    loa[t]  = bf2f(lob[t * 128 + l]);
    lobv[t] = bf2f(lob[t * 128 + 64 + l]);
  }
  const float wa = Wa[l], wb = Wa[64 + l];
  float sc[16];
  #pragma unroll
  for (int t = 0; t < 16; ++t) sc[t] = rsum64(loa[t] * wa + lobv[t] * wb) + ba[0];
  float mx = sc[0];
  #pragma unroll
  for (int t = 1; t < 16; ++t) mx = fmaxf(mx, sc[t]);
  float den = 0.f;
  #pragma unroll
  for (int t = 0; t < 16; ++t) { sc[t] = __expf(sc[t] - mx); den += sc[t]; }
  const float inv = 1.f / den;
  float ca = 0.f, cb = 0.f;
  #pragma unroll
  for (int t = 0; t < 16; ++t) {
    float wgt = sc[t] * inv;
    ca = fmaf(wgt, loa[t], ca);
    cb = fmaf(wgt, lobv[t], cb);
  }
  __shared__ float zsh[160];
  __shared__ float hsk[64];
  __shared__ float skin[16];
  zsh[l] = ca; zsh[64 + l] = cb;
  const int bb = q / 1000, nn = q - bb * 1000;
  if (l < 13) skin[l] = X[(size_t)((bb * 16 + 15) * 1000 + nn) * 32 + l];
  __syncthreads();
  float h1 = bs1[l];
  for (int c = 0; c < 13; ++c) h1 = fmaf(skin[c], HWT[c * 64 + l], h1);
  h1 = geluf(h1);
  hsk[l] = h1;
  __syncthreads();
  if (l < 32) {
    float a = bs2[l];
    for (int jj = 0; jj < 64; ++jj) a = fmaf(hsk[jj], HWT[832 + jj * 32 + l], a);
    zsh[128 + l] = a;
  }
  __syncthreads();
  float hh = bh1[l];
  for (int r = 0; r < 160; ++r) hh = fmaf(zsh[r], HWT[2880 + r * 64 + l], hh);
  hh = geluf(hh);
  float s = rsum64(hh * Wh2[l]);
  if (l == 0) out[q] = s + bh2[0];
}

// ---------------- launch ----------------
extern "C" void kernel_launch(void* const* d_in, const int* in_sizes, int n_in,
                              void* d_out, int out_size, void* d_ws, size_t ws_size,
                              hipStream_t stream)
{
  const float* x    = (const float*)d_in[0];
  const int*   ei   = (const int*)d_in[1];
  const float* Wp   = (const float*)d_in[2];
  const float* bp   = (const float*)d_in[3];
  const float* Wl1  = (const float*)d_in[4];
  const float* Wr1  = (const float*)d_in[5];
  const float* a1   = (const float*)d_in[6];
  const float* bg1  = (const float*)d_in[7];
  const float* g1   = (const float*)d_in[8];
  const float* be1  = (const float*)d_in[9];
  const float* m1   = (const float*)d_in[10];
  const float* v1   = (const float*)d_in[11];
  const float* Wl2  = (const float*)d_in[12];
  const float* Wr2  = (const float*)d_in[13];
  const float* a2   = (const float*)d_in[14];
  const float* bg2  = (const float*)d_in[15];
  const float* g2   = (const float*)d_in[16];
  const float* be2  = (const float*)d_in[17];
  const float* m2   = (const float*)d_in[18];
  const float* v2   = (const float*)d_in[19];
  const float* Wih0 = (const float*)d_in[20];
  const float* Whh0 = (const float*)d_in[21];
  const float* bih0 = (const float*)d_in[22];
  const float* bhh0 = (const float*)d_in[23];
  const float* Wih1 = (const float*)d_in[24];
  const float* Whh1 = (const float*)d_in[25];
  const float* bih1 = (const float*)d_in[26];
  const float* bhh1 = (const float*)d_in[27];
  const float* Wa   = (const float*)d_in[28];
  const float* ba   = (const float*)d_in[29];
  const float* Ws1  = (const float*)d_in[30];
  const float* bs1  = (const float*)d_in[31];
  const float* Ws2  = (const float*)d_in[32];
  const float* bs2  = (const float*)d_in[33];
  const float* Wh1  = (const float*)d_in[34];
  const float* bh1  = (const float*)d_in[35];
  const float* Wh2  = (const float*)d_in[36];
  const float* bh2  = (const float*)d_in[37];

  float* ws = (float*)d_ws;
  int* srcD   = (int*)(ws + O_SRCD);
  int* dstD   = (int*)(ws + O_DSTD);
  int* counts = (int*)(ws + O_COUNTS);
  int* offs   = (int*)(ws + O_OFFS);
  int* curs   = (int*)(ws + O_CURS);
  int* esrc   = (int*)(ws + O_EIDX);
  float* PW1  = ws + O_PW1;
  unsigned short* PW2Bu = (unsigned short*)(ws + O_PW2);          // 131072 bf16
  unsigned short* PHHBu = (unsigned short*)(ws + O_LW);           // 262144 bf16
  unsigned short* PWBu  = (unsigned short*)(ws + O_LW + 131072u); // 262144 bf16
  float* BC   = ws + O_BCOMB;
  float* ABF  = ws + O_ABF;
  float* HWT  = ws + O_HWT;
  unsigned short* XL1u = (unsigned short*)(ws + O_BIG0);          // fp16
  unsigned short* XR1u = (unsigned short*)(ws + O_BIG1);
  unsigned short* H1u  = (unsigned short*)(ws + O_BIG2);
  unsigned short* XPu  = (unsigned short*)(ws + O_BIG3);
  unsigned short* Hresu = (unsigned short*)(ws + O_BIG4);
  unsigned short* XL2u = (unsigned short*)(ws + O_BIG0);          // fp16
  unsigned short* XR2u = (unsigned short*)(ws + O_BIG0 + 8192000u);
  unsigned short* PREh = (unsigned short*)(ws + O_BIG0);
  unsigned short* H1SEQu = (unsigned short*)(ws + O_BIG2);
  unsigned short* LOu  = (unsigned short*)(ws + O_BIG3);
  float* SXL1 = ws + O_SXL;               // [64000][2] (pre-scaled by 0.6)
  float* SXL2 = ws + O_SXL + 128000u;     // [64000]    (pre-scaled by 0.6)
  float* C1F  = ws + O_SXL + 192000u;     // [2][32]
  float* C2F  = ws + O_SXL + 192064u;     // [256]
  float* outp = (float*)d_out;

  prep_edges<<<67, 256, 0, stream>>>(ei, srcD, dstD, counts);
  hist_kernel<<<67, 256, 0, stream>>>(dstD, counts);
  scan_kernel<<<1, 1024, 0, stream>>>(counts, offs, curs);
  fill_kernel<<<67, 256, 0, stream>>>(srcD, dstD, curs, esrc);
  pack_kernel<<<1024, 256, 0, stream>>>(Wl1, Wr1, Wp, Wl2, Wr2,
      Wih0, Whh0, bih0, bhh0, Wih1, Whh1, bih1, bhh1,
      g1, be1, m1, v1, bg1, g2, be2, m2, v2, bg2,
      Ws1, Ws2, Wh1, a1, a2, PW1, PW2Bu, PHHBu, PWBu, BC, ABF, HWT, C1F, C2F);
  proj1_kernel<<<4000, 320, 0, stream>>>(x, PW1, bp, C1F, XL1u, XR1u, XPu, SXL1);
  gat1_kernel<<<dim3(250, 64), 256, 0, stream>>>(XL1u, XR1u, SXL1, esrc, offs, a1, ABF,
                                                 C2F, H1u, SXL2);
  proj2_kernel<<<2000, 512, 0, stream>>>(H1u, PW2Bu, XL2u, XR2u);
  gat2_kernel<<<dim3(250, 64), 256, 0, stream>>>(XL2u, XR2u, SXL2, esrc, offs, a2, ABF,
                                                 XPu, Hresu);
  gemm_pre_kernel<<<2000, 512, 0, stream>>>(Hresu, PWBu, BC, PREh);
  rec2_kernel<<<250, 512, 0, stream>>>(PREh, PHHBu, H1SEQu);
  gemm_pre_kernel<<<2000, 512, 0, stream>>>(H1SEQu, PWBu + 131072u, BC + 512, PREh);
  rec2_kernel<<<250, 512, 0, stream>>>(PREh, PHHBu + 131072u, LOu);
  attn_kernel<<<4000, 64, 0, stream>>>(LOu, x, Wa, ba, bs1, bs2, bh1, bh2, Wh2, HWT, outp);
}